// Round 11
// baseline (1231.268 us; speedup 1.0000x reference)
//
#include <hip/hip_runtime.h>
#include <math.h>

#define S_   400
#define B_   16
#define T_   32
#define H_   256
#define A_   100
#define G_   50
#define VF_  100
#define V_   50000
#define BV_  50050

#define L2E   1.44269504088896f
#define L2E2  2.88539008177793f

// ---- ws offsets (floats) ----
#define WS_H0S   0          // [2][256][16] h-major state, parity buffered
#define WS_C0S   8192
#define WS_H1S   16384
#define WS_C1S   24576
#define WS_Y0    32768      // [32][256][16] layer0 outputs (h-major)
#define WS_OD    163840     // [32][256][16] layer1 outputs (h-major)
#define WS_WT0   294912     // [256][1024] k-major w_hh0, col c -> j=(c&3)*256+(c>>2)
#define WS_WTI1  557056     // [256][1024] k-major w_ih1 (same col map)
#define WS_WTH1  819200     // [256][1024] k-major w_hh1 (same col map)
#define WS_WODT  1081344    // [256][100]  W_attn[:,512:768]^T
#define WS_WV1T  1106944    // [768][100]  W_v1^T
#define WS_BASE2 1183744    // [16][50][400] uint: packed bf16 pair, pre-scaled by 2log2e
#define WS_ODP2  1503744    // [32*16][100] (od@WODT)*2log2e
#define WS_ATTN  1554944    // [16][32][400]
#define WS_H1B   1759744    // [512][128] bf16 (stored as shorts) = 32768 float slots
#define WS_PGEN  1792512    // [512]
#define WS_VSUM  1793024    // [512]
#define WS_SYNC  1793536    // 2 ints: barrier count, generation
#define WS_TOTAL 1793544

// ---- out offsets (floats) ----
#define OUT_CL   25625600
#define OUT_COV  25626112
#define OUT_HID  25632512
#define OUT_CELL 25640704
// first 8*512*512 floats of out are used as ctx-partial scratch (overwritten by vocab pass B later)
#define CTXP_SZ  262144

typedef __attribute__((ext_vector_type(8))) short bf16x8;
typedef __attribute__((ext_vector_type(4))) float f32x4;

__device__ __forceinline__ float fexp2(float x){ return __builtin_amdgcn_exp2f(x); }
__device__ __forceinline__ float frcp (float x){ return __builtin_amdgcn_rcpf(x); }
__device__ __forceinline__ float sigm (float x){ return frcp(1.f + fexp2(-L2E*x)); }
__device__ __forceinline__ float tanhx(float x){ return fmaf(-2.f, frcp(1.f + fexp2(L2E2*x)), 1.f); }
__device__ __forceinline__ unsigned short cvt_bf16(float x){
  unsigned u = __float_as_uint(x);
  u += 0x7FFFu + ((u >> 16) & 1u);
  return (unsigned short)(u >> 16);
}
__device__ __forceinline__ unsigned pack2bf(float lo, float hi){
  return ((unsigned)cvt_bf16(hi) << 16) | (unsigned)cvt_bf16(lo);
}

__device__ __forceinline__ float bredSum(float v, float* red){
  #pragma unroll
  for (int m = 32; m >= 1; m >>= 1) v += __shfl_xor(v, m);
  __syncthreads();
  if ((threadIdx.x & 63) == 0) red[threadIdx.x >> 6] = v;
  __syncthreads();
  float r = 0.f;
  int nw = blockDim.x >> 6;
  for (int k = 0; k < nw; ++k) r += red[k];
  return r;
}

// device-scope generation barrier for 192 co-resident WGs
__device__ __forceinline__ void gridbar(int* cnt, int* gen, int target){
  __syncthreads();
  if (threadIdx.x == 0){
    __threadfence();
    int prev = __hip_atomic_fetch_add(cnt, 1, __ATOMIC_ACQ_REL, __HIP_MEMORY_SCOPE_AGENT);
    if (prev == 191){
      __hip_atomic_store(cnt, 0, __ATOMIC_RELAXED, __HIP_MEMORY_SCOPE_AGENT);
      __hip_atomic_store(gen, target, __ATOMIC_RELEASE, __HIP_MEMORY_SCOPE_AGENT);
    } else {
      while (__hip_atomic_load(gen, __ATOMIC_ACQUIRE, __HIP_MEMORY_SCOPE_AGENT) < target)
        __builtin_amdgcn_s_sleep(2);
    }
  }
  __syncthreads();
}

// ---------------- prep: weight transposes + reduce_enc + small copies + enc_base ----------------
__global__ __launch_bounds__(256) void k_prep_enc(const float* __restrict__ he,
    const float* __restrict__ ce, const float* __restrict__ b_reduce,
    const float* __restrict__ W_reduce,
    const float* __restrict__ W_attn, const float* __restrict__ W_v1,
    const float* __restrict__ w_hh0, const float* __restrict__ w_ih1,
    const float* __restrict__ w_hh1,
    const float* __restrict__ enc, const float* __restrict__ b_attn,
    float* __restrict__ ws){
  int bx = blockIdx.x, tid = threadIdx.x;
  __shared__ float tile[64*65];
  __shared__ float encs[16][132];
  __shared__ float was[50][132];
  __shared__ float hA[256], hB[256], cA[256], cB[256];
  if (bx < 192){
    int m = bx >> 6, t6 = bx & 63;
    int kb = t6 & 3, cb = t6 >> 2;
    const float* src = (m == 0) ? w_hh0 : (m == 1) ? w_ih1 : w_hh1;
    int dstoff = (m == 0) ? WS_WT0 : (m == 1) ? WS_WTI1 : WS_WTH1;
    for (int o = tid; o < 4096; o += 256){
      int cc = o >> 6, kk = o & 63;
      int c = cb*64 + cc;
      int j = (c & 3)*256 + (c >> 2);
      tile[cc*65 + kk] = src[j*256 + kb*64 + kk];
    }
    __syncthreads();
    for (int o = tid; o < 4096; o += 256){
      int kk = o >> 6, cc = o & 63;
      ws[dstoff + (kb*64 + kk)*1024 + cb*64 + cc] = tile[cc*65 + kk];
    }
    return;
  }
  if (bx < 224){
    int bx2 = bx - 192;
    int l = bx2 >> 4, b = bx2 & 15, j = tid;
    hA[tid] = he[(l*B_ + b)*H_ + tid];
    hB[tid] = he[((l+2)*B_ + b)*H_ + tid];
    cA[tid] = ce[(l*B_ + b)*H_ + tid];
    cB[tid] = ce[((l+2)*B_ + b)*H_ + tid];
    __syncthreads();
    float ah = b_reduce[j], ac = b_reduce[j];
    const float4* row = (const float4*)(W_reduce + j*512);
    #pragma unroll 8
    for (int k4 = 0; k4 < 64; ++k4){
      float4 wa = row[k4];
      float4 wb = row[64 + k4];
      int k = k4*4;
      ah += wa.x*hA[k] + wa.y*hA[k+1] + wa.z*hA[k+2] + wa.w*hA[k+3];
      ac += wa.x*cA[k] + wa.y*cA[k+1] + wa.z*cA[k+2] + wa.w*cA[k+3];
      ah += wb.x*hB[k] + wb.y*hB[k+1] + wb.z*hB[k+2] + wb.w*hB[k+3];
      ac += wb.x*cB[k] + wb.y*cB[k+1] + wb.z*cB[k+2] + wb.w*cB[k+3];
    }
    if (l == 0){ ws[WS_H0S + j*16 + b] = ah; ws[WS_C0S + j*16 + b] = ac; }
    else       { ws[WS_H1S + j*16 + b] = ah; ws[WS_C1S + j*16 + b] = ac; }
    return;
  }
  if (bx < 627){
    int i = (bx - 224)*256 + tid;
    if (i < 25600){ int k = i/100, a = i%100; ws[WS_WODT + i] = W_attn[a*769 + 512 + k]; return; }
    i -= 25600;
    if (i < 76800){ int k = i/100, f = i%100; ws[WS_WV1T + i] = W_v1[f*768 + k]; return; }
    i -= 76800;
    if (i < 512){ ws[WS_VSUM + i] = 0.f; return; }
    i -= 512;
    if (i < 2){ ((int*)(ws + WS_SYNC))[i] = 0; return; }
    return;
  }
  // ---- enc_base: packed bf16 [b][p2][s], value = (enc@Wattn + b_attn)*2log2e ----
  int r = bx - 627;                      // 800 = st + 25*(ah + 2*b)
  int st = r % 25, rem = r / 25;
  int ah = rem & 1, b = rem >> 1;
  int s_base = st*16;
  bool act = tid < 200;
  int sg = tid & 7, ag = tid >> 3;
  int sl = sg*2, al = ag*2;
  float acc00=0.f, acc01=0.f, acc10=0.f, acc11=0.f;
  for (int kc = 0; kc < 4; ++kc){
    int k0 = kc*128;
    __syncthreads();
    for (int o = tid; o < 512; o += 256){
      int rr = o >> 5, c4 = (o & 31)*4;
      float4 v = *(const float4*)(enc + ((s_base + rr)*B_ + b)*512 + k0 + c4);
      *(float4*)&encs[rr][c4] = v;
    }
    for (int o = tid; o < 6400; o += 256){
      int rr = o >> 7, c = o & 127;
      was[rr][c] = W_attn[(ah*50 + rr)*769 + k0 + c];
    }
    __syncthreads();
    if (act){
      for (int k = 0; k < 128; ++k){
        float e0 = encs[sl][k], e1 = encs[sl+1][k];
        float w0 = was[al][k],  w1 = was[al+1][k];
        acc00 = fmaf(e0, w0, acc00); acc01 = fmaf(e0, w1, acc01);
        acc10 = fmaf(e1, w0, acc10); acc11 = fmaf(e1, w1, acc11);
      }
    }
  }
  if (act){
    int a = ah*50 + al, s = s_base + sl;
    float b0 = b_attn[a], b1 = b_attn[a+1];
    int p2 = ah*25 + (al >> 1);
    unsigned* bu = (unsigned*)(ws + WS_BASE2) + b*20000;
    bu[p2*400 + s    ] = pack2bf((acc00 + b0)*L2E2, (acc01 + b1)*L2E2);
    bu[p2*400 + s + 1] = pack2bf((acc10 + b0)*L2E2, (acc11 + b1)*L2E2);
  }
}

// ---------------- persistent LSTM: all 32 steps of both layers, 192 WGs, grid barrier;
// WGs 0-63 layer0 (16 cols each, k-split 2), WGs 64-191 layer1 (8 cols each, k-split 2);
// final phase computes odp2 ----------------
__global__ __launch_bounds__(256, 1) void k_lstm_all(const float* __restrict__ input_dec,
    const float* __restrict__ w_ih0, const float* __restrict__ b_ih0, const float* __restrict__ b_hh0,
    const float* __restrict__ b_ih1, const float* __restrict__ b_hh1,
    float* __restrict__ ws, float* __restrict__ out){
  int wgs = blockIdx.x;
  int tid = threadIdx.x;
  __shared__ float hs[4096];
  __shared__ float ys[4096];
  __shared__ float gv[288];
  __shared__ float xs[16];
  int* cnt = (int*)(ws + WS_SYNC);
  int* gen = cnt + 1;
  if (wgs < 64){
    int w = wgs;
    int ks = tid & 1, cl = (tid >> 1) & 15, bg = tid >> 5;  // 2 x 16 x 8
    int c = w*16 + cl;
    int g = cl & 3;
    int h = w*4 + (cl >> 2);
    int j = g*256 + h;
    float bias0 = b_ih0[j] + b_hh0[j];
    float wih = w_ih0[j];
    const float* wp = ws + WS_WT0 + ks*131072 + c;
    for (int p = 0; p <= 32; ++p){
      if (p < 32){
        int par = p & 1, npar = par ^ 1;
        for (int o = tid; o < 1024; o += 256)
          *(float4*)&hs[o*4] = *(const float4*)&ws[WS_H0S + par*4096 + o*4];
        if (tid < 16) xs[tid] = input_dec[p*16 + tid];
        __syncthreads();
        float a0, a1;
        if (ks == 0){
          a0 = fmaf(xs[bg*2],   wih, bias0);
          a1 = fmaf(xs[bg*2+1], wih, bias0);
        } else { a0 = 0.f; a1 = 0.f; }
        const float* hp = hs + ks*2048 + bg*2;
        #pragma unroll 16
        for (int k = 0; k < 128; ++k){
          float wv = wp[k*1024];
          float2 hv = *(const float2*)&hp[k*16];
          a0 = fmaf(wv, hv.x, a0); a1 = fmaf(wv, hv.y, a1);
        }
        a0 += __shfl_xor(a0, 1);
        a1 += __shfl_xor(a1, 1);
        if (ks == 0){
          gv[cl*18 + bg*2    ] = a0;
          gv[cl*18 + bg*2 + 1] = a1;
        }
        __syncthreads();
        if (tid < 64){
          int b = tid & 15, hl = tid >> 4;       // hl 0..3
          float gi = gv[(hl*4+0)*18 + b], gf = gv[(hl*4+1)*18 + b];
          float gg = gv[(hl*4+2)*18 + b], go = gv[(hl*4+3)*18 + b];
          int hidx = w*4 + hl;
          float cold = ws[WS_C0S + par*4096 + hidx*16 + b];
          float ig = sigm(gi), fg = sigm(gf), gt = tanhx(gg), og = sigm(go);
          float cn = fmaf(fg, cold, ig*gt);
          float hn = og * tanhx(cn);
          ws[WS_C0S + npar*4096 + hidx*16 + b] = cn;
          ws[WS_H0S + npar*4096 + hidx*16 + b] = hn;
          ws[WS_Y0 + p*4096 + hidx*16 + b] = hn;
          if (p == 31){
            out[OUT_HID  + b*256 + hidx] = hn;
            out[OUT_CELL + b*256 + hidx] = cn;
          }
        }
      }
      gridbar(cnt, gen, p + 1);
    }
  } else {
    int u = wgs - 64;                        // 0..127
    int ks = tid & 1, cl = (tid >> 1) & 7, b = tid >> 4;   // 2 x 8 x 16
    int c = u*8 + cl;
    int g = cl & 3;
    int h = u*2 + (cl >> 2);
    int j = g*256 + h;
    float bias1 = b_ih1[j] + b_hh1[j];
    const float* wi = ws + WS_WTI1 + ks*131072 + c;
    const float* wh = ws + WS_WTH1 + ks*131072 + c;
    for (int p = 0; p <= 32; ++p){
      if (p >= 1){
        int q = p - 1;
        int par = q & 1, npar = par ^ 1;
        for (int o = tid; o < 1024; o += 256){
          *(float4*)&ys[o*4] = *(const float4*)&ws[WS_Y0 + q*4096 + o*4];
          *(float4*)&hs[o*4] = *(const float4*)&ws[WS_H1S + par*4096 + o*4];
        }
        __syncthreads();
        float ai = (ks == 0) ? bias1 : 0.f;
        float ah2 = 0.f;
        const float* yp = ys + ks*2048 + b;
        const float* hp = hs + ks*2048 + b;
        #pragma unroll 16
        for (int k = 0; k < 128; ++k){
          ai  = fmaf(wi[k*1024], yp[k*16], ai);
          ah2 = fmaf(wh[k*1024], hp[k*16], ah2);
        }
        float tot = ai + ah2;
        tot += __shfl_xor(tot, 1);
        if (ks == 0) gv[cl*17 + b] = tot;
        __syncthreads();
        if (tid < 32){
          int b2 = tid & 15, hl = tid >> 4;      // hl 0..1
          float gi = gv[(hl*4+0)*17 + b2], gf = gv[(hl*4+1)*17 + b2];
          float gg = gv[(hl*4+2)*17 + b2], go = gv[(hl*4+3)*17 + b2];
          int hidx = u*2 + hl;
          float cold = ws[WS_C1S + par*4096 + hidx*16 + b2];
          float ig = sigm(gi), fg = sigm(gf), gt = tanhx(gg), og = sigm(go);
          float cn = fmaf(fg, cold, ig*gt);
          float hn = og * tanhx(cn);
          ws[WS_C1S + npar*4096 + hidx*16 + b2] = cn;
          ws[WS_H1S + npar*4096 + hidx*16 + b2] = hn;
          ws[WS_OD + q*4096 + hidx*16 + b2] = hn;
          if (q == 31){
            out[OUT_HID  + 4096 + b2*256 + hidx] = hn;
            out[OUT_CELL + 4096 + b2*256 + hidx] = cn;
          }
        }
      }
      gridbar(cnt, gen, p + 1);
    }
  }
  // ---- odp phase: odp2[r][a] = (od[r] @ WODT) * 2log2e ----
  for (int r = wgs; r < 512; r += 192){
    int t = r >> 4, b = r & 15;
    __syncthreads();
    hs[tid] = ws[WS_OD + t*4096 + tid*16 + b];
    __syncthreads();
    if (tid < 100){
      float acc = 0.f;
      for (int k = 0; k < 256; ++k) acc = fmaf(ws[WS_WODT + k*100 + tid], hs[k], acc);
      ws[WS_ODP2 + r*100 + tid] = acc * L2E2;
    }
  }
}

// ---------------- attention recurrence v6: one WG per batch, ONE barrier/step,
// half-pair in same wave (shfl_xor 32), base2 LDS bf16, t-indexed den/cls slots ----------------
__global__ __launch_bounds__(832) void k_attn(const float* __restrict__ amask,
    const float* __restrict__ W_attn, const float* __restrict__ wout_g,
    float* __restrict__ out, float* __restrict__ ws){
  int b = blockIdx.x;
  int tid = threadIdx.x;
  int w = tid >> 6, l = tid & 63;
  int sl = l & 31, half = l >> 5;
  int s = w*32 + sl;                      // 13 waves cover s<416
  bool valid = s < 400;
  int h25 = half*25, a0 = half*50;
  __shared__ unsigned ba2L[20000];        // [p2 0..49][s 0..399] packed bf16 pair
  __shared__ float4 f4[2][100];
  __shared__ float wcwo[200];
  __shared__ float den[32], cls[32];
  const unsigned* src = (const unsigned*)(ws + WS_BASE2) + b*20000;
  for (int o = tid; o < 20000; o += 832) ba2L[o] = src[o];
  if (tid < 100){
    wcwo[tid]       = W_attn[tid*769 + 768] * L2E2;
    wcwo[100 + tid] = -2.f * wout_g[tid];
  }
  if (tid < 32){ den[tid] = 0.f; cls[tid] = 0.f; }
  float woSum = 0.f;
  #pragma unroll 10
  for (int a = 0; a < 100; ++a) woSum += wout_g[a];
  float amL = valid ? amask[s*16 + b] * L2E : 0.f;
  float cov = 0.f;
  int sI = valid ? s : 0;
  __syncthreads();
  if (tid < 100){
    float od = ws[WS_ODP2 + b*100 + tid];   // t=0 row
    f4[0][tid] = make_float4(od, wcwo[tid], wcwo[100 + tid], 0.f);
  }
  __syncthreads();

  for (int t = 0; t < T_; ++t){
    int par = t & 1;
    float ep0 = 0.f, ep1 = 0.f;
    if (valid){
      #pragma unroll
      for (int i2 = 0; i2 < 25; ++i2){
        unsigned d = ba2L[(h25 + i2)*400 + sI];
        float4 qa = f4[par][a0 + 2*i2];
        float4 qb = f4[par][a0 + 2*i2 + 1];
        float blo = __uint_as_float(d << 16);
        float bhi = __uint_as_float(d & 0xffff0000u);
        float xa = fmaf(qa.y, cov, blo + qa.x);
        float xb = fmaf(qb.y, cov, bhi + qb.x);
        ep0 = fmaf(qa.z, frcp(1.f + fexp2(xa)), ep0);
        ep1 = fmaf(qb.z, frcp(1.f + fexp2(xb)), ep1);
      }
    }
    float e = ep0 + ep1;
    e += __shfl_xor(e, 32);               // combine the two a-halves of this s
    float ex = 0.f;
    if (valid) ex = fexp2(fmaf(woSum + e, L2E, amL));
    float ps = half ? 0.f : ex;
    #pragma unroll
    for (int m = 32; m >= 1; m >>= 1) ps += __shfl_xor(ps, m);
    if (l == 0) atomicAdd(&den[t], ps);
    if (tid < 100 && t < T_-1){
      float od = ws[WS_ODP2 + ((t+1)*16 + b)*100 + tid];
      f4[par^1][tid] = make_float4(od, wcwo[tid], wcwo[100 + tid], 0.f);
    }
    __syncthreads();                      // den[t] ready; f4[par^1] ready
    float inv = frcp(den[t]);
    float at = ex * inv;
    float cl = fminf(at, cov);
    cov += at;
    float p2 = half ? 0.f : cl;
    #pragma unroll
    for (int m = 32; m >= 1; m >>= 1) p2 += __shfl_xor(p2, m);
    if (l == 0) atomicAdd(&cls[t], p2);
    if (half == 0 && valid) ws[WS_ATTN + (b*32 + t)*400 + s] = at;
    if (tid == 0 && t > 0) out[OUT_CL + (t-1)*16 + b] = cls[t-1];
  }
  __syncthreads();
  if (tid == 0) out[OUT_CL + 31*16 + b] = cls[31];
  if (half == 0 && valid) out[OUT_COV + s*16 + b] = cov;
}

// ---------------- context partials into out-scratch: ctxp[sc][t*16+b][512] ----------------
__global__ __launch_bounds__(256) void k_ctx(const float* __restrict__ enc,
    const float* __restrict__ ws, float* __restrict__ ctxp){
  int b = blockIdx.x, jh = blockIdx.y, sc = blockIdx.z;   // (16,2,8)
  int tid = threadIdx.x;
  __shared__ float at[32*52];
  for (int o = tid; o < 1600; o += 256){
    int t = o/50, s2 = o%50;
    at[t*52 + s2] = ws[WS_ATTN + (b*32 + t)*400 + sc*50 + s2];
  }
  __syncthreads();
  int j = jh*256 + tid;
  float acc[32];
  #pragma unroll
  for (int t = 0; t < 32; ++t) acc[t] = 0.f;
  for (int s2 = 0; s2 < 50; ++s2){
    float evv = enc[((sc*50 + s2)*16 + b)*512 + j];
    #pragma unroll
    for (int t = 0; t < 32; ++t) acc[t] = fmaf(at[t*52 + s2], evv, acc[t]);
  }
  #pragma unroll
  for (int t = 0; t < 32; ++t)
    ctxp[sc*CTXP_SZ + (t*16 + b)*512 + j] = acc[t];
}

// ---------------- pgen + h1 (vocab hidden, bf16 padded) per (t,b) ----------------
__global__ __launch_bounds__(256) void k_pgen_h1(const float* __restrict__ input_dec,
    const float* __restrict__ emb, const float* __restrict__ b_v1,
    const float* __restrict__ W_pgen, const float* __restrict__ b_pgen,
    const float* __restrict__ ctxp, float* __restrict__ ws){
  int row = blockIdx.x, tid = threadIdx.x;
  int t = row >> 4, b = row & 15;
  __shared__ float pv[768], el[50], red[16];
  pv[tid] = ws[WS_OD + t*4096 + tid*16 + b];
  float c0 = 0.f, c1 = 0.f;
  #pragma unroll
  for (int sc = 0; sc < 8; ++sc){
    c0 += ctxp[sc*CTXP_SZ + row*512 + tid];
    c1 += ctxp[sc*CTXP_SZ + row*512 + 256 + tid];
  }
  pv[256 + tid] = c0;
  pv[512 + tid] = c1;
  int tok = (int)input_dec[row];
  if (tid < 50) el[tid] = emb[tok*50 + tid];
  __syncthreads();
  float p = 0.f;
  for (int k = tid; k < 818; k += 256){
    float x = (k < 512) ? pv[256 + k] : (k < 768) ? pv[k - 512] : el[k - 768];
    p = fmaf(W_pgen[k], x, p);
  }
  p = bredSum(p, red);
  if (tid == 0) ws[WS_PGEN + row] = sigm(p + b_pgen[0]);
  short* hb = (short*)(ws + WS_H1B);
  if (tid < 100){
    float acc = b_v1[tid];
    for (int k = 0; k < 768; ++k) acc = fmaf(ws[WS_WV1T + k*100 + tid], pv[k], acc);
    hb[row*128 + tid] = (short)cvt_bf16(acc);
  } else if (tid < 128){
    hb[row*128 + tid] = 0;
  }
}

// ---------------- pass A: per-row exp2-sums, LDS-staged bf16 W_v2 tile ----------------
__global__ __launch_bounds__(256) void k_vsum(const float* __restrict__ W_v2,
    const float* __restrict__ b_v2, float* __restrict__ ws){
  int tid = threadIdx.x;
  int wave = tid >> 6, l = tid & 63;
  int lane_m = l & 15, lq = l >> 4;
  int vblock0 = blockIdx.x*256;
  int r0base = blockIdx.y*256;
  __shared__ short wt[256*136];          // rows padded to 136 shorts (272B)
  __shared__ float biasL[256];
  __shared__ float rsum[256];
  for (int o = tid; o < 4352; o += 256)
    ((int4*)wt)[o] = make_int4(0,0,0,0);
  {
    int v = vblock0 + tid;
    biasL[tid] = (v < V_) ? b_v2[v] : 0.f;
    rsum[tid] = 0.f;
  }
  __syncthreads();
  int vcount = V_ - vblock0; if (vcount > 256) vcount = 256;
  for (int o = tid; o < vcount*25; o += 256){
    int r = o/25, kq = o - r*25;
    float4 v4 = *(const float4*)(W_v2 + (size_t)(vblock0 + r)*100 + kq*4);
    short4 s4;
    s4.x = (short)cvt_bf16(v4.x); s4.y = (short)cvt_bf16(v4.y);
    s4.z = (short)cvt_bf16(v4.z); s4.w = (short)cvt_bf16(v4.w);
    *(short4*)&wt[r*136 + kq*4] = s4;
  }
  __syncthreads();
  bf16x8 bf[4][4];
  float bias[4];
  int vv[4];
  #pragma unroll
  for (int nt = 0; nt < 4; ++nt){
    int vl = wave*64 + nt*16 + lane_m;
    vv[nt] = vblock0 + vl;
    bias[nt] = biasL[vl];
    #pragma unroll
    for (int kk = 0; kk < 4; ++kk)
      bf[nt][kk] = *(const bf16x8*)&wt[vl*136 + kk*32 + lq*8];
  }
  const short* hws = (const short*)(ws + WS_H1B);
  for (int rg = 0; rg < 16; ++rg){
    int r0 = r0base + rg*16;
    bf16x8 af[4];
    #pragma unroll
    for (int kk = 0; kk < 4; ++kk)
      af[kk] = *(const bf16x8*)(hws + (r0 + lane_m)*128 + kk*32 + lq*8);
    float es[4] = {0.f, 0.f, 0.f, 0.f};
    #pragma unroll
    for (int nt = 0; nt < 4; ++nt){
      f32x4 c = {bias[nt], bias[nt], bias[nt], bias[nt]};
      #pragma unroll
      for (int kk = 0; kk < 4; ++kk)
        c = __builtin_amdgcn_mfma_f32_16x16x32_bf16(af[kk], bf[nt][kk], c, 0, 0, 0);
      if (vv[nt] < V_){
        #pragma unroll
        for (int j = 0; j < 4; ++j) es[j] += fexp2(c[j] * L2E);
      }
    }
    #pragma unroll
    for (int m = 1; m <= 8; m <<= 1){
      #pragma unroll
      for (int j = 0; j < 4; ++j) es[j] += __shfl_xor(es[j], m);
    }
    if (lane_m == 0){
      #pragma unroll
      for (int j = 0; j < 4; ++j)
        atomicAdd(&rsum[rg*16 + lq*4 + j], es[j]);
    }
  }
  __syncthreads();
  atomicAdd(ws + WS_VSUM + r0base + tid, rsum[tid]);
}

// ---------------- pass B: recompute logits, write softmax*pgen, LDS-staged tile + coalesced stores ----------------
__global__ __launch_bounds__(256) void k_vwrite(const float* __restrict__ W_v2,
    const float* __restrict__ b_v2, const float* __restrict__ ws, float* __restrict__ out){
  int tid = threadIdx.x;
  int wave = tid >> 6, l = tid & 63;
  int lane_m = l & 15, lq = l >> 4;
  int vblock0 = blockIdx.x*256;
  int r0base = blockIdx.y*256;
  __shared__ short wt[256*136];
  __shared__ float biasL[256];
  __shared__ float scs[256];
  __shared__ float stg[16][260];
  for (int o = tid; o < 4352; o += 256)
    ((int4*)wt)[o] = make_int4(0,0,0,0);
  {
    int v = vblock0 + tid;
    biasL[tid] = (v < V_) ? b_v2[v] : 0.f;
    int r = r0base + tid;
    scs[tid] = ws[WS_PGEN + r] / ws[WS_VSUM + r];
  }
  __syncthreads();
  int vcount = V_ - vblock0; if (vcount > 256) vcount = 256;
  for (int o = tid; o < vcount*25; o += 256){
    int r = o/25, kq = o - r*25;
    float4 v4 = *(const float4*)(W_v2 + (size_t)(vblock0 + r)*100 + kq*4);
    short4 s4;
    s4.x = (short)cvt_bf16(v4.x); s4.y = (short)cvt_bf16(v4.y);
    s4.z = (short)cvt_bf16(v4.z); s4.w = (short)cvt_bf16(v4.w);
    *(short4*)&wt[r*136 + kq*4] = s4;
  }
  __syncthreads();
  bf16x8 bf[4][4];
  float bias[4];
  int vv[4];
  #pragma unroll
  for (int nt = 0; nt < 4; ++nt){
    int vl = wave*64 + nt*16 + lane_m;
    vv[nt] = vblock0 + vl;
    bias[nt] = biasL[vl];
    #pragma unroll
    for (int kk = 0; kk < 4; ++kk)
      bf[nt][kk] = *(const bf16x8*)&wt[vl*136 + kk*32 + lq*8];
  }
  const short* hws = (const short*)(ws + WS_H1B);
  int limit = BV_ - vblock0;            // valid col count in [0,256]
  if (limit > 256) limit = 256;
  for (int rg = 0; rg < 16; ++rg){
    int r0 = r0base + rg*16;
    bf16x8 af[4];
    #pragma unroll
    for (int kk = 0; kk < 4; ++kk)
      af[kk] = *(const bf16x8*)(hws + (r0 + lane_m)*128 + kk*32 + lq*8);
    #pragma unroll
    for (int nt = 0; nt < 4; ++nt){
      f32x4 c = {bias[nt], bias[nt], bias[nt], bias[nt]};
      #pragma unroll
      for (int kk = 0; kk < 4; ++kk)
        c = __builtin_amdgcn_mfma_f32_16x16x32_bf16(af[kk], bf[nt][kk], c, 0, 0, 0);
      bool gen = vv[nt] < V_;
      #pragma unroll
      for (int j = 0; j < 4; ++j){
        int rloc = lq*4 + j;
        float p = gen ? fexp2(c[j] * L2E) * scs[rg*16 + rloc] : 0.f;
        stg[rloc][wave*64 + nt*16 + lane_m] = p;
      }
    }
    __syncthreads();
    #pragma unroll
    for (int rep = 0; rep < 4; ++rep){
      int o = rep*256 + tid;
      int rr = o >> 6, c4 = (o & 63)*4;
      size_t base = (size_t)(r0base + rg*16 + rr)*BV_ + vblock0;
      if (c4 + 4 <= limit){
        float4 val = *(const float4*)&stg[rr][c4];
        *(float4*)&out[base + c4] = val;
      } else {
        for (int e = 0; e < 4; ++e)
          if (c4 + e < limit) out[base + c4 + e] = stg[rr][c4 + e];
      }
    }
    __syncthreads();
  }
}

// ---------------- copy-distribution scatter ----------------
__global__ __launch_bounds__(256) void k_scatter(const int* __restrict__ real_index,
    const float* __restrict__ ws, float* __restrict__ out){
  int i = blockIdx.x*256 + threadIdx.x;   // 16*32*400
  int b = i / 12800, r = i % 12800, t = r / 400, s = r % 400;
  float at = ws[WS_ATTN + i];
  float w = 1.f - ws[WS_PGEN + t*16 + b];
  int col = real_index[s*16 + b];
  atomicAdd(out + (size_t)(t*16 + b)*BV_ + col, at*w);
}

extern "C" void kernel_launch(void* const* d_in, const int* in_sizes, int n_in,
                              void* d_out, int out_size, void* d_ws, size_t ws_size,
                              hipStream_t stream){
  const float* output_enc = (const float*)d_in[0];
  const int*   real_index = (const int*)d_in[1];
  const float* input_dec  = (const float*)d_in[3];
  const float* hidden_enc = (const float*)d_in[4];
  const float* cell_enc   = (const float*)d_in[5];
  const float* att_mask   = (const float*)d_in[6];
  const float* emb        = (const float*)d_in[7];
  const float* W_reduce   = (const float*)d_in[8];
  const float* b_reduce   = (const float*)d_in[9];
  const float* w_ih0      = (const float*)d_in[10];
  const float* w_hh0      = (const float*)d_in[11];
  const float* b_ih0      = (const float*)d_in[12];
  const float* b_hh0      = (const float*)d_in[13];
  const float* w_ih1      = (const float*)d_in[14];
  const float* w_hh1      = (const float*)d_in[15];
  const float* b_ih1      = (const float*)d_in[16];
  const float* b_hh1      = (const float*)d_in[17];
  const float* W_attn     = (const float*)d_in[18];
  const float* b_attn     = (const float*)d_in[19];
  const float* w_attn_out = (const float*)d_in[20];
  const float* W_v1       = (const float*)d_in[21];
  const float* b_v1       = (const float*)d_in[22];
  const float* W_v2       = (const float*)d_in[23];
  const float* b_v2       = (const float*)d_in[24];
  const float* W_pgen     = (const float*)d_in[25];
  const float* b_pgen     = (const float*)d_in[26];
  float* out = (float*)d_out;
  float* ws  = (float*)d_ws;
  if (ws_size < (size_t)WS_TOTAL * sizeof(float)) return;

  k_prep_enc<<<dim3(1427), dim3(256), 0, stream>>>(hidden_enc, cell_enc, b_reduce, W_reduce,
                                                   W_attn, W_v1, w_hh0, w_ih1, w_hh1,
                                                   output_enc, b_attn, ws);
  k_lstm_all<<<dim3(192), dim3(256), 0, stream>>>(input_dec, w_ih0, b_ih0, b_hh0,
                                                  b_ih1, b_hh1, ws, out);
  k_attn<<<dim3(16), dim3(832), 0, stream>>>(att_mask, W_attn, w_attn_out, out, ws);
  k_ctx<<<dim3(16, 2, 8), dim3(256), 0, stream>>>(output_enc, ws, out);
  k_pgen_h1<<<dim3(512), dim3(256), 0, stream>>>(input_dec, emb, b_v1, W_pgen, b_pgen, out, ws);
  k_vsum<<<dim3(196, 2), dim3(256), 0, stream>>>(W_v2, b_v2, ws);
  k_vwrite<<<dim3(196, 2), dim3(256), 0, stream>>>(W_v2, b_v2, ws, out);
  k_scatter<<<dim3(800), dim3(256), 0, stream>>>(real_index, ws, out);
}

// Round 12
// 863.847 us; speedup vs baseline: 1.4253x; 1.4253x over previous
//
#include <hip/hip_runtime.h>
#include <math.h>

#define S_   400
#define B_   16
#define T_   32
#define H_   256
#define A_   100
#define G_   50
#define VF_  100
#define V_   50000
#define BV_  50050

#define L2E   1.44269504088896f
#define L2E2  2.88539008177793f

// ---- ws offsets (floats) ----
#define WS_H0S   0          // [2][256][16] h-major state, parity buffered
#define WS_C0S   8192
#define WS_H1S   16384
#define WS_C1S   24576
#define WS_Y0    32768      // [32][256][16] layer0 outputs (h-major)
#define WS_OD    163840     // [32][256][16] layer1 outputs (h-major)
#define WS_WT0   294912     // [256][1024] k-major w_hh0, col c -> j=(c&3)*256+(c>>2)
#define WS_WTI1  557056     // [256][1024] k-major w_ih1 (same col map)
#define WS_WTH1  819200     // [256][1024] k-major w_hh1 (same col map)
#define WS_WODT  1081344    // [256][100]  W_attn[:,512:768]^T
#define WS_WV1T  1106944    // [768][100]  W_v1^T
#define WS_BASE2 1183744    // [16][50][400] uint: packed bf16 pair, pre-scaled by 2log2e
#define WS_ODP2  1503744    // [32*16][100] (od@WODT)*2log2e
#define WS_ATTN  1554944    // [16][32][400]
#define WS_H1B   1759744    // [512][128] bf16 (stored as shorts) = 32768 float slots
#define WS_PGEN  1792512    // [512]
#define WS_VSUM  1793024    // [512]
#define WS_TOTAL 1793536

// ---- out offsets (floats) ----
#define OUT_CL   25625600
#define OUT_COV  25626112
#define OUT_HID  25632512
#define OUT_CELL 25640704
// first 8*512*512 floats of out are used as ctx-partial scratch (overwritten by vocab pass B later)
#define CTXP_SZ  262144

typedef __attribute__((ext_vector_type(8))) short bf16x8;
typedef __attribute__((ext_vector_type(4))) float f32x4;

__device__ __forceinline__ float fexp2(float x){ return __builtin_amdgcn_exp2f(x); }
__device__ __forceinline__ float frcp (float x){ return __builtin_amdgcn_rcpf(x); }
__device__ __forceinline__ float sigm (float x){ return frcp(1.f + fexp2(-L2E*x)); }
__device__ __forceinline__ float tanhx(float x){ return fmaf(-2.f, frcp(1.f + fexp2(L2E2*x)), 1.f); }
__device__ __forceinline__ unsigned short cvt_bf16(float x){
  unsigned u = __float_as_uint(x);
  u += 0x7FFFu + ((u >> 16) & 1u);
  return (unsigned short)(u >> 16);
}
__device__ __forceinline__ unsigned pack2bf(float lo, float hi){
  return ((unsigned)cvt_bf16(hi) << 16) | (unsigned)cvt_bf16(lo);
}

__device__ __forceinline__ float bredSum(float v, float* red){
  #pragma unroll
  for (int m = 32; m >= 1; m >>= 1) v += __shfl_xor(v, m);
  __syncthreads();
  if ((threadIdx.x & 63) == 0) red[threadIdx.x >> 6] = v;
  __syncthreads();
  float r = 0.f;
  int nw = blockDim.x >> 6;
  for (int k = 0; k < nw; ++k) r += red[k];
  return r;
}

// ---------------- prep: weight transposes + reduce_enc + small copies ----------------
__global__ __launch_bounds__(256) void k_prep(const float* __restrict__ he,
    const float* __restrict__ ce, const float* __restrict__ b_reduce,
    const float* __restrict__ W_reduce,
    const float* __restrict__ W_attn, const float* __restrict__ W_v1,
    const float* __restrict__ w_hh0, const float* __restrict__ w_ih1,
    const float* __restrict__ w_hh1, float* __restrict__ ws){
  int bx = blockIdx.x, tid = threadIdx.x;
  __shared__ float tile[64*65];
  __shared__ float hA[256], hB[256], cA[256], cB[256];
  if (bx < 192){
    int m = bx >> 6, t6 = bx & 63;
    int kb = t6 & 3, cb = t6 >> 2;
    const float* src = (m == 0) ? w_hh0 : (m == 1) ? w_ih1 : w_hh1;
    int dstoff = (m == 0) ? WS_WT0 : (m == 1) ? WS_WTI1 : WS_WTH1;
    for (int o = tid; o < 4096; o += 256){
      int cc = o >> 6, kk = o & 63;
      int c = cb*64 + cc;
      int j = (c & 3)*256 + (c >> 2);
      tile[cc*65 + kk] = src[j*256 + kb*64 + kk];
    }
    __syncthreads();
    for (int o = tid; o < 4096; o += 256){
      int kk = o >> 6, cc = o & 63;
      ws[dstoff + (kb*64 + kk)*1024 + cb*64 + cc] = tile[cc*65 + kk];
    }
    return;
  }
  if (bx < 224){
    int bx2 = bx - 192;
    int l = bx2 >> 4, b = bx2 & 15, j = tid;
    hA[tid] = he[(l*B_ + b)*H_ + tid];
    hB[tid] = he[((l+2)*B_ + b)*H_ + tid];
    cA[tid] = ce[(l*B_ + b)*H_ + tid];
    cB[tid] = ce[((l+2)*B_ + b)*H_ + tid];
    __syncthreads();
    float ah = b_reduce[j], ac = b_reduce[j];
    const float4* row = (const float4*)(W_reduce + j*512);
    #pragma unroll 8
    for (int k4 = 0; k4 < 64; ++k4){
      float4 wa = row[k4];
      float4 wb = row[64 + k4];
      int k = k4*4;
      ah += wa.x*hA[k] + wa.y*hA[k+1] + wa.z*hA[k+2] + wa.w*hA[k+3];
      ac += wa.x*cA[k] + wa.y*cA[k+1] + wa.z*cA[k+2] + wa.w*cA[k+3];
      ah += wb.x*hB[k] + wb.y*hB[k+1] + wb.z*hB[k+2] + wb.w*hB[k+3];
      ac += wb.x*cB[k] + wb.y*cB[k+1] + wb.z*cB[k+2] + wb.w*cB[k+3];
    }
    if (l == 0){ ws[WS_H0S + j*16 + b] = ah; ws[WS_C0S + j*16 + b] = ac; }
    else       { ws[WS_H1S + j*16 + b] = ah; ws[WS_C1S + j*16 + b] = ac; }
    return;
  }
  int i = (bx - 224)*256 + tid;
  if (i < 25600){ int k = i/100, a = i%100; ws[WS_WODT + i] = W_attn[a*769 + 512 + k]; return; }
  i -= 25600;
  if (i < 76800){ int k = i/100, f = i%100; ws[WS_WV1T + i] = W_v1[f*768 + k]; return; }
  i -= 76800;
  if (i < 512){ ws[WS_VSUM + i] = 0.f; return; }
}

// ---------------- LSTM phase p (split-K) + enc_base slices riding along:
// WGs 0-63 layer0 step p (16 cols each, k-split 2),
// WGs 64-191 layer1 step p-1 (8 cols each, k-split 2),
// WGs 192-216: enc_base block r = p*25 + (wgs-192), for p<32 ----------------
__global__ __launch_bounds__(256, 1) void k_lstm4(const float* __restrict__ input_dec,
    const float* __restrict__ w_ih0, const float* __restrict__ b_ih0, const float* __restrict__ b_hh0,
    const float* __restrict__ b_ih1, const float* __restrict__ b_hh1,
    const float* __restrict__ enc, const float* __restrict__ W_attn,
    const float* __restrict__ b_attn,
    float* __restrict__ ws, float* __restrict__ out, int p){
  int wgs = blockIdx.x;
  int tid = threadIdx.x;
  __shared__ float smem[8720];
  if (wgs < 64){
    if (p >= T_) return;
    float* hs = smem;             // 4096
    float* gv = smem + 4096;      // 288
    float* xs = smem + 4400;      // 16
    int w = wgs;
    int par = p & 1, npar = par ^ 1;
    for (int o = tid; o < 1024; o += 256)
      *(float4*)&hs[o*4] = *(const float4*)&ws[WS_H0S + par*4096 + o*4];
    if (tid < 16) xs[tid] = input_dec[p*16 + tid];
    __syncthreads();
    int ks = tid & 1, cl = (tid >> 1) & 15, bg = tid >> 5;  // 2 x 16 x 8
    int c = w*16 + cl;
    int g = cl & 3, h = w*4 + (cl >> 2);
    int j = g*256 + h;
    float a0, a1;
    if (ks == 0){
      float bias = b_ih0[j] + b_hh0[j];
      float wih = w_ih0[j];
      a0 = fmaf(xs[bg*2],   wih, bias);
      a1 = fmaf(xs[bg*2+1], wih, bias);
    } else { a0 = 0.f; a1 = 0.f; }
    const float* wp = ws + WS_WT0 + ks*131072 + c;
    const float* hp = hs + ks*2048 + bg*2;
    #pragma unroll 16
    for (int k = 0; k < 128; ++k){
      float wv = wp[k*1024];
      float2 hv = *(const float2*)&hp[k*16];
      a0 = fmaf(wv, hv.x, a0); a1 = fmaf(wv, hv.y, a1);
    }
    a0 += __shfl_xor(a0, 1);
    a1 += __shfl_xor(a1, 1);
    if (ks == 0){
      gv[cl*18 + bg*2    ] = a0;
      gv[cl*18 + bg*2 + 1] = a1;
    }
    __syncthreads();
    if (tid < 64){
      int b = tid & 15, hl = tid >> 4;       // hl 0..3
      float gi = gv[(hl*4+0)*18 + b], gf = gv[(hl*4+1)*18 + b];
      float gg = gv[(hl*4+2)*18 + b], go = gv[(hl*4+3)*18 + b];
      int hidx = w*4 + hl;
      float cold = ws[WS_C0S + par*4096 + hidx*16 + b];
      float ig = sigm(gi), fg = sigm(gf), gt = tanhx(gg), og = sigm(go);
      float cn = fmaf(fg, cold, ig*gt);
      float hn = og * tanhx(cn);
      ws[WS_C0S + npar*4096 + hidx*16 + b] = cn;
      ws[WS_H0S + npar*4096 + hidx*16 + b] = hn;
      ws[WS_Y0 + p*4096 + hidx*16 + b] = hn;
      if (p == T_-1){
        out[OUT_HID  + b*256 + hidx] = hn;
        out[OUT_CELL + b*256 + hidx] = cn;
      }
    }
  } else if (wgs < 192){
    int q = p - 1;
    if (q < 0) return;
    float* ys = smem;             // 4096
    float* hs = smem + 4096;      // 4096
    float* gv = smem + 8192;      // 288
    int u = wgs - 64;                        // 0..127
    int par = q & 1, npar = par ^ 1;
    for (int o = tid; o < 1024; o += 256){
      *(float4*)&ys[o*4] = *(const float4*)&ws[WS_Y0 + q*4096 + o*4];
      *(float4*)&hs[o*4] = *(const float4*)&ws[WS_H1S + par*4096 + o*4];
    }
    __syncthreads();
    int ks = tid & 1, cl = (tid >> 1) & 7, b = tid >> 4;   // 2 x 8 x 16
    int c = u*8 + cl;
    int g = cl & 3, h = u*2 + (cl >> 2);
    int j = g*256 + h;
    float ai = (ks == 0) ? (b_ih1[j] + b_hh1[j]) : 0.f;
    float ah2 = 0.f;
    const float* wi = ws + WS_WTI1 + ks*131072 + c;
    const float* wh = ws + WS_WTH1 + ks*131072 + c;
    const float* yp = ys + ks*2048 + b;
    const float* hp = hs + ks*2048 + b;
    #pragma unroll 16
    for (int k = 0; k < 128; ++k){
      ai  = fmaf(wi[k*1024], yp[k*16], ai);
      ah2 = fmaf(wh[k*1024], hp[k*16], ah2);
    }
    float tot = ai + ah2;
    tot += __shfl_xor(tot, 1);
    if (ks == 0) gv[cl*17 + b] = tot;
    __syncthreads();
    if (tid < 32){
      int b2 = tid & 15, hl = tid >> 4;      // hl 0..1
      float gi = gv[(hl*4+0)*17 + b2], gf = gv[(hl*4+1)*17 + b2];
      float gg = gv[(hl*4+2)*17 + b2], go = gv[(hl*4+3)*17 + b2];
      int hidx = u*2 + hl;
      float cold = ws[WS_C1S + par*4096 + hidx*16 + b2];
      float ig = sigm(gi), fg = sigm(gf), gt = tanhx(gg), og = sigm(go);
      float cn = fmaf(fg, cold, ig*gt);
      float hn = og * tanhx(cn);
      ws[WS_C1S + npar*4096 + hidx*16 + b2] = cn;
      ws[WS_H1S + npar*4096 + hidx*16 + b2] = hn;
      ws[WS_OD + q*4096 + hidx*16 + b2] = hn;
      if (q == T_-1){
        out[OUT_HID  + 4096 + b2*256 + hidx] = hn;
        out[OUT_CELL + 4096 + b2*256 + hidx] = cn;
      }
    }
  } else {
    // ---- enc_base slice: r = p*25 + (wgs-192); 800 = st + 25*(ah + 2*b) ----
    if (p >= 32) return;
    int r = p*25 + (wgs - 192);
    float* encs = smem;           // 16*132 = 2112
    float* was  = smem + 2112;    // 50*132 = 6600
    int st = r % 25, rem = r / 25;
    int ah = rem & 1, b = rem >> 1;
    int s_base = st*16;
    bool act = tid < 200;
    int sg = tid & 7, ag = tid >> 3;
    int sl = sg*2, al = ag*2;
    float acc00=0.f, acc01=0.f, acc10=0.f, acc11=0.f;
    for (int kc = 0; kc < 4; ++kc){
      int k0 = kc*128;
      __syncthreads();
      for (int o = tid; o < 512; o += 256){
        int rr = o >> 5, c4 = (o & 31)*4;
        float4 v = *(const float4*)(enc + ((s_base + rr)*B_ + b)*512 + k0 + c4);
        *(float4*)&encs[rr*132 + c4] = v;
      }
      for (int o = tid; o < 6400; o += 256){
        int rr = o >> 7, c = o & 127;
        was[rr*132 + c] = W_attn[(ah*50 + rr)*769 + k0 + c];
      }
      __syncthreads();
      if (act){
        for (int k = 0; k < 128; ++k){
          float e0 = encs[sl*132 + k], e1 = encs[(sl+1)*132 + k];
          float w0 = was[al*132 + k],  w1 = was[(al+1)*132 + k];
          acc00 = fmaf(e0, w0, acc00); acc01 = fmaf(e0, w1, acc01);
          acc10 = fmaf(e1, w0, acc10); acc11 = fmaf(e1, w1, acc11);
        }
      }
    }
    if (act){
      int a = ah*50 + al, s = s_base + sl;
      float b0 = b_attn[a], b1 = b_attn[a+1];
      int p2 = ah*25 + (al >> 1);
      unsigned* bu = (unsigned*)(ws + WS_BASE2) + b*20000;
      bu[p2*400 + s    ] = pack2bf((acc00 + b0)*L2E2, (acc01 + b1)*L2E2);
      bu[p2*400 + s + 1] = pack2bf((acc10 + b0)*L2E2, (acc11 + b1)*L2E2);
    }
  }
}

// ---------------- odp2[t*16+b][a] = (od @ W_attn[:,512:768]^T) * 2log2e ----------------
__global__ __launch_bounds__(256) void k_odp(float* __restrict__ ws){
  int row = blockIdx.x;        // 512 = t*16+b
  int t = row >> 4, b = row & 15;
  int tid = threadIdx.x;
  __shared__ float odl[256];
  odl[tid] = ws[WS_OD + t*4096 + tid*16 + b];
  __syncthreads();
  if (tid < 100){
    float acc = 0.f;
    for (int k = 0; k < 256; ++k) acc = fmaf(ws[WS_WODT + k*100 + tid], odl[k], acc);
    ws[WS_ODP2 + row*100 + tid] = acc * L2E2;
  }
}

// ---------------- attention recurrence v7: one WG per batch, ONE barrier/step,
// half-pair in same wave (shfl_xor 32), base2 LDS bf16, 16 waves ----------------
__global__ __launch_bounds__(1024) void k_attn(const float* __restrict__ amask,
    const float* __restrict__ W_attn, const float* __restrict__ wout_g,
    float* __restrict__ out, float* __restrict__ ws){
  int b = blockIdx.x;
  int tid = threadIdx.x;
  int w = tid >> 6, l = tid & 63;
  int sl = l & 31, half = l >> 5;
  int s = w*32 + sl;                      // 16 waves cover s<512
  bool valid = s < 400;
  int h25 = half*25, a0 = half*50;
  __shared__ unsigned ba2L[20000];        // [p2 0..49][s 0..399] packed bf16 pair
  __shared__ float4 f4[2][100];
  __shared__ float wcwo[200];
  __shared__ float den[32], cls[32];
  const unsigned* src = (const unsigned*)(ws + WS_BASE2) + b*20000;
  for (int o = tid; o < 20000; o += 1024) ba2L[o] = src[o];
  if (tid < 100){
    wcwo[tid]       = W_attn[tid*769 + 768] * L2E2;
    wcwo[100 + tid] = -2.f * wout_g[tid];
  }
  if (tid < 32){ den[tid] = 0.f; cls[tid] = 0.f; }
  float woSum = 0.f;
  #pragma unroll 10
  for (int a = 0; a < 100; ++a) woSum += wout_g[a];
  float amL = valid ? amask[s*16 + b] * L2E : 0.f;
  float cov = 0.f;
  int sI = valid ? s : 0;
  __syncthreads();
  if (tid < 100){
    float od = ws[WS_ODP2 + b*100 + tid];   // t=0 row
    f4[0][tid] = make_float4(od, wcwo[tid], wcwo[100 + tid], 0.f);
  }
  __syncthreads();

  for (int t = 0; t < T_; ++t){
    int par = t & 1;
    float ep0 = 0.f, ep1 = 0.f;
    if (valid){
      #pragma unroll
      for (int i2 = 0; i2 < 25; ++i2){
        unsigned d = ba2L[(h25 + i2)*400 + sI];
        float4 qa = f4[par][a0 + 2*i2];
        float4 qb = f4[par][a0 + 2*i2 + 1];
        float blo = __uint_as_float(d << 16);
        float bhi = __uint_as_float(d & 0xffff0000u);
        float xa = fmaf(qa.y, cov, blo + qa.x);
        float xb = fmaf(qb.y, cov, bhi + qb.x);
        ep0 = fmaf(qa.z, frcp(1.f + fexp2(xa)), ep0);
        ep1 = fmaf(qb.z, frcp(1.f + fexp2(xb)), ep1);
      }
    }
    float e = ep0 + ep1;
    e += __shfl_xor(e, 32);               // combine the two a-halves of this s
    float ex = 0.f;
    if (valid) ex = fexp2(fmaf(woSum + e, L2E, amL));
    float ps = half ? 0.f : ex;
    #pragma unroll
    for (int m = 32; m >= 1; m >>= 1) ps += __shfl_xor(ps, m);
    if (l == 0) atomicAdd(&den[t], ps);
    if (tid < 100 && t < T_-1){
      float od = ws[WS_ODP2 + ((t+1)*16 + b)*100 + tid];
      f4[par^1][tid] = make_float4(od, wcwo[tid], wcwo[100 + tid], 0.f);
    }
    __syncthreads();                      // den[t] ready; f4[par^1] ready
    float inv = frcp(den[t]);
    float at = ex * inv;
    float cl = fminf(at, cov);
    cov += at;
    float p2 = half ? 0.f : cl;
    #pragma unroll
    for (int m = 32; m >= 1; m >>= 1) p2 += __shfl_xor(p2, m);
    if (l == 0) atomicAdd(&cls[t], p2);
    if (half == 0 && valid) ws[WS_ATTN + (b*32 + t)*400 + s] = at;
    if (tid == 0 && t > 0) out[OUT_CL + (t-1)*16 + b] = cls[t-1];
  }
  __syncthreads();
  if (tid == 0) out[OUT_CL + 31*16 + b] = cls[31];
  if (half == 0 && valid) out[OUT_COV + s*16 + b] = cov;
}

// ---------------- context partials into out-scratch: ctxp[sc][t*16+b][512] ----------------
__global__ __launch_bounds__(256) void k_ctx(const float* __restrict__ enc,
    const float* __restrict__ ws, float* __restrict__ ctxp){
  int b = blockIdx.x, jh = blockIdx.y, sc = blockIdx.z;   // (16,2,8)
  int tid = threadIdx.x;
  __shared__ float at[32*52];
  for (int o = tid; o < 1600; o += 256){
    int t = o/50, s2 = o%50;
    at[t*52 + s2] = ws[WS_ATTN + (b*32 + t)*400 + sc*50 + s2];
  }
  __syncthreads();
  int j = jh*256 + tid;
  float acc[32];
  #pragma unroll
  for (int t = 0; t < 32; ++t) acc[t] = 0.f;
  for (int s2 = 0; s2 < 50; ++s2){
    float evv = enc[((sc*50 + s2)*16 + b)*512 + j];
    #pragma unroll
    for (int t = 0; t < 32; ++t) acc[t] = fmaf(at[t*52 + s2], evv, acc[t]);
  }
  #pragma unroll
  for (int t = 0; t < 32; ++t)
    ctxp[sc*CTXP_SZ + (t*16 + b)*512 + j] = acc[t];
}

// ---------------- pgen + h1 (vocab hidden, bf16 padded) per (t,b) ----------------
__global__ __launch_bounds__(256) void k_pgen_h1(const float* __restrict__ input_dec,
    const float* __restrict__ emb, const float* __restrict__ b_v1,
    const float* __restrict__ W_pgen, const float* __restrict__ b_pgen,
    const float* __restrict__ ctxp, float* __restrict__ ws){
  int row = blockIdx.x, tid = threadIdx.x;
  int t = row >> 4, b = row & 15;
  __shared__ float pv[768], el[50], red[16];
  pv[tid] = ws[WS_OD + t*4096 + tid*16 + b];
  float c0 = 0.f, c1 = 0.f;
  #pragma unroll
  for (int sc = 0; sc < 8; ++sc){
    c0 += ctxp[sc*CTXP_SZ + row*512 + tid];
    c1 += ctxp[sc*CTXP_SZ + row*512 + 256 + tid];
  }
  pv[256 + tid] = c0;
  pv[512 + tid] = c1;
  int tok = (int)input_dec[row];
  if (tid < 50) el[tid] = emb[tok*50 + tid];
  __syncthreads();
  float p = 0.f;
  for (int k = tid; k < 818; k += 256){
    float x = (k < 512) ? pv[256 + k] : (k < 768) ? pv[k - 512] : el[k - 768];
    p = fmaf(W_pgen[k], x, p);
  }
  p = bredSum(p, red);
  if (tid == 0) ws[WS_PGEN + row] = sigm(p + b_pgen[0]);
  short* hb = (short*)(ws + WS_H1B);
  if (tid < 100){
    float acc = b_v1[tid];
    for (int k = 0; k < 768; ++k) acc = fmaf(ws[WS_WV1T + k*100 + tid], pv[k], acc);
    hb[row*128 + tid] = (short)cvt_bf16(acc);
  } else if (tid < 128){
    hb[row*128 + tid] = 0;
  }
}

// ---------------- pass A: per-row exp2-sums, LDS-staged bf16 W_v2 tile ----------------
__global__ __launch_bounds__(256) void k_vsum(const float* __restrict__ W_v2,
    const float* __restrict__ b_v2, float* __restrict__ ws){
  int tid = threadIdx.x;
  int wave = tid >> 6, l = tid & 63;
  int lane_m = l & 15, lq = l >> 4;
  int vblock0 = blockIdx.x*256;
  int r0base = blockIdx.y*256;
  __shared__ short wt[256*136];          // rows padded to 136 shorts (272B)
  __shared__ float biasL[256];
  __shared__ float rsum[256];
  for (int o = tid; o < 4352; o += 256)
    ((int4*)wt)[o] = make_int4(0,0,0,0);
  {
    int v = vblock0 + tid;
    biasL[tid] = (v < V_) ? b_v2[v] : 0.f;
    rsum[tid] = 0.f;
  }
  __syncthreads();
  int vcount = V_ - vblock0; if (vcount > 256) vcount = 256;
  for (int o = tid; o < vcount*25; o += 256){
    int r = o/25, kq = o - r*25;
    float4 v4 = *(const float4*)(W_v2 + (size_t)(vblock0 + r)*100 + kq*4);
    short4 s4;
    s4.x = (short)cvt_bf16(v4.x); s4.y = (short)cvt_bf16(v4.y);
    s4.z = (short)cvt_bf16(v4.z); s4.w = (short)cvt_bf16(v4.w);
    *(short4*)&wt[r*136 + kq*4] = s4;
  }
  __syncthreads();
  bf16x8 bf[4][4];
  float bias[4];
  int vv[4];
  #pragma unroll
  for (int nt = 0; nt < 4; ++nt){
    int vl = wave*64 + nt*16 + lane_m;
    vv[nt] = vblock0 + vl;
    bias[nt] = biasL[vl];
    #pragma unroll
    for (int kk = 0; kk < 4; ++kk)
      bf[nt][kk] = *(const bf16x8*)&wt[vl*136 + kk*32 + lq*8];
  }
  const short* hws = (const short*)(ws + WS_H1B);
  for (int rg = 0; rg < 16; ++rg){
    int r0 = r0base + rg*16;
    bf16x8 af[4];
    #pragma unroll
    for (int kk = 0; kk < 4; ++kk)
      af[kk] = *(const bf16x8*)(hws + (r0 + lane_m)*128 + kk*32 + lq*8);
    float es[4] = {0.f, 0.f, 0.f, 0.f};
    #pragma unroll
    for (int nt = 0; nt < 4; ++nt){
      f32x4 c = {bias[nt], bias[nt], bias[nt], bias[nt]};
      #pragma unroll
      for (int kk = 0; kk < 4; ++kk)
        c = __builtin_amdgcn_mfma_f32_16x16x32_bf16(af[kk], bf[nt][kk], c, 0, 0, 0);
      if (vv[nt] < V_){
        #pragma unroll
        for (int j = 0; j < 4; ++j) es[j] += fexp2(c[j] * L2E);
      }
    }
    #pragma unroll
    for (int m = 1; m <= 8; m <<= 1){
      #pragma unroll
      for (int j = 0; j < 4; ++j) es[j] += __shfl_xor(es[j], m);
    }
    if (lane_m == 0){
      #pragma unroll
      for (int j = 0; j < 4; ++j)
        atomicAdd(&rsum[rg*16 + lq*4 + j], es[j]);
    }
  }
  __syncthreads();
  atomicAdd(ws + WS_VSUM + r0base + tid, rsum[tid]);
}

// ---------------- pass B: recompute logits, write softmax*pgen, LDS-staged tile + coalesced stores ----------------
__global__ __launch_bounds__(256) void k_vwrite(const float* __restrict__ W_v2,
    const float* __restrict__ b_v2, const float* __restrict__ ws, float* __restrict__ out){
  int tid = threadIdx.x;
  int wave = tid >> 6, l = tid & 63;
  int lane_m = l & 15, lq = l >> 4;
  int vblock0 = blockIdx.x*256;
  int r0base = blockIdx.y*256;
  __shared__ short wt[256*136];
  __shared__ float biasL[256];
  __shared__ float scs[256];
  __shared__ float stg[16][260];
  for (int o = tid; o < 4352; o += 256)
    ((int4*)wt)[o] = make_int4(0,0,0,0);
  {
    int v = vblock0 + tid;
    biasL[tid] = (v < V_) ? b_v2[v] : 0.f;
    int r = r0base + tid;
    scs[tid] = ws[WS_PGEN + r] / ws[WS_VSUM + r];
  }
  __syncthreads();
  int vcount = V_ - vblock0; if (vcount > 256) vcount = 256;
  for (int o = tid; o < vcount*25; o += 256){
    int r = o/25, kq = o - r*25;
    float4 v4 = *(const float4*)(W_v2 + (size_t)(vblock0 + r)*100 + kq*4);
    short4 s4;
    s4.x = (short)cvt_bf16(v4.x); s4.y = (short)cvt_bf16(v4.y);
    s4.z = (short)cvt_bf16(v4.z); s4.w = (short)cvt_bf16(v4.w);
    *(short4*)&wt[r*136 + kq*4] = s4;
  }
  __syncthreads();
  bf16x8 bf[4][4];
  float bias[4];
  int vv[4];
  #pragma unroll
  for (int nt = 0; nt < 4; ++nt){
    int vl = wave*64 + nt*16 + lane_m;
    vv[nt] = vblock0 + vl;
    bias[nt] = biasL[vl];
    #pragma unroll
    for (int kk = 0; kk < 4; ++kk)
      bf[nt][kk] = *(const bf16x8*)&wt[vl*136 + kk*32 + lq*8];
  }
  const short* hws = (const short*)(ws + WS_H1B);
  int limit = BV_ - vblock0;            // valid col count in [0,256]
  if (limit > 256) limit = 256;
  for (int rg = 0; rg < 16; ++rg){
    int r0 = r0base + rg*16;
    bf16x8 af[4];
    #pragma unroll
    for (int kk = 0; kk < 4; ++kk)
      af[kk] = *(const bf16x8*)(hws + (r0 + lane_m)*128 + kk*32 + lq*8);
    #pragma unroll
    for (int nt = 0; nt < 4; ++nt){
      f32x4 c = {bias[nt], bias[nt], bias[nt], bias[nt]};
      #pragma unroll
      for (int kk = 0; kk < 4; ++kk)
        c = __builtin_amdgcn_mfma_f32_16x16x32_bf16(af[kk], bf[nt][kk], c, 0, 0, 0);
      bool gen = vv[nt] < V_;
      #pragma unroll
      for (int j = 0; j < 4; ++j){
        int rloc = lq*4 + j;
        float p = gen ? fexp2(c[j] * L2E) * scs[rg*16 + rloc] : 0.f;
        stg[rloc][wave*64 + nt*16 + lane_m] = p;
      }
    }
    __syncthreads();
    #pragma unroll
    for (int rep = 0; rep < 4; ++rep){
      int o = rep*256 + tid;
      int rr = o >> 6, c4 = (o & 63)*4;
      size_t base = (size_t)(r0base + rg*16 + rr)*BV_ + vblock0;
      if (c4 + 4 <= limit){
        float4 val = *(const float4*)&stg[rr][c4];
        *(float4*)&out[base + c4] = val;
      } else {
        for (int e = 0; e < 4; ++e)
          if (c4 + e < limit) out[base + c4 + e] = stg[rr][c4 + e];
      }
    }
    __syncthreads();
  }
}

// ---------------- copy-distribution scatter ----------------
__global__ __launch_bounds__(256) void k_scatter(const int* __restrict__ real_index,
    const float* __restrict__ ws, float* __restrict__ out){
  int i = blockIdx.x*256 + threadIdx.x;   // 16*32*400
  int b = i / 12800, r = i % 12800, t = r / 400, s = r % 400;
  float at = ws[WS_ATTN + i];
  float w = 1.f - ws[WS_PGEN + t*16 + b];
  int col = real_index[s*16 + b];
  atomicAdd(out + (size_t)(t*16 + b)*BV_ + col, at*w);
}

extern "C" void kernel_launch(void* const* d_in, const int* in_sizes, int n_in,
                              void* d_out, int out_size, void* d_ws, size_t ws_size,
                              hipStream_t stream){
  const float* output_enc = (const float*)d_in[0];
  const int*   real_index = (const int*)d_in[1];
  const float* input_dec  = (const float*)d_in[3];
  const float* hidden_enc = (const float*)d_in[4];
  const float* cell_enc   = (const float*)d_in[5];
  const float* att_mask   = (const float*)d_in[6];
  const float* emb        = (const float*)d_in[7];
  const float* W_reduce   = (const float*)d_in[8];
  const float* b_reduce   = (const float*)d_in[9];
  const float* w_ih0      = (const float*)d_in[10];
  const float* w_hh0      = (const float*)d_in[11];
  const float* b_ih0      = (const float*)d_in[12];
  const float* b_hh0      = (const float*)d_in[13];
  const float* w_ih1      = (const float*)d_in[14];
  const float* w_hh1      = (const float*)d_in[15];
  const float* b_ih1      = (const float*)d_in[16];
  const float* b_hh1      = (const float*)d_in[17];
  const float* W_attn     = (const float*)d_in[18];
  const float* b_attn     = (const float*)d_in[19];
  const float* w_attn_out = (const float*)d_in[20];
  const float* W_v1       = (const float*)d_in[21];
  const float* b_v1       = (const float*)d_in[22];
  const float* W_v2       = (const float*)d_in[23];
  const float* b_v2       = (const float*)d_in[24];
  const float* W_pgen     = (const float*)d_in[25];
  const float* b_pgen     = (const float*)d_in[26];
  float* out = (float*)d_out;
  float* ws  = (float*)d_ws;
  if (ws_size < (size_t)WS_TOTAL * sizeof(float)) return;

  k_prep<<<dim3(626), dim3(256), 0, stream>>>(hidden_enc, cell_enc, b_reduce, W_reduce,
                                              W_attn, W_v1, w_hh0, w_ih1, w_hh1, ws);
  for (int p = 0; p <= T_; ++p)
    k_lstm4<<<dim3(217), dim3(256), 0, stream>>>(input_dec, w_ih0, b_ih0, b_hh0,
                                                 b_ih1, b_hh1, output_enc, W_attn,
                                                 b_attn, ws, out, p);
  k_odp<<<dim3(512), dim3(256), 0, stream>>>(ws);
  k_attn<<<dim3(16), dim3(1024), 0, stream>>>(att_mask, W_attn, w_attn_out, out, ws);
  k_ctx<<<dim3(16, 2, 8), dim3(256), 0, stream>>>(output_enc, ws, out);
  k_pgen_h1<<<dim3(512), dim3(256), 0, stream>>>(input_dec, emb, b_v1, W_pgen, b_pgen, out, ws);
  k_vsum<<<dim3(196, 2), dim3(256), 0, stream>>>(W_v2, b_v2, ws);
  k_vwrite<<<dim3(196, 2), dim3(256), 0, stream>>>(W_v2, b_v2, ws, out);
  k_scatter<<<dim3(800), dim3(256), 0, stream>>>(real_index, ws, out);
}

// Round 13
// 696.783 us; speedup vs baseline: 1.7671x; 1.2398x over previous
//
#include <hip/hip_runtime.h>
#include <math.h>

#define S_   400
#define B_   16
#define T_   32
#define H_   256
#define A_   100
#define G_   50
#define VF_  100
#define V_   50000
#define BV_  50050

#define L2E   1.44269504088896f
#define L2E2  2.88539008177793f

// ---- ws offsets (floats) ----
#define WS_H0S   0          // [2][256][16] h-major state, parity buffered
#define WS_C0S   8192
#define WS_H1S   16384
#define WS_C1S   24576
#define WS_Y0    32768      // [32][256][16] layer0 outputs (h-major)
#define WS_OD    163840     // [32][256][16] layer1 outputs (h-major)
#define WS_WT0   294912     // [256][1024] k-major w_hh0, col c -> j=(c&3)*256+(c>>2)
#define WS_WTI1  557056     // [256][1024] k-major w_ih1 (same col map)
#define WS_WTH1  819200     // [256][1024] k-major w_hh1 (same col map)
#define WS_WODT  1081344    // [256][100]  W_attn[:,512:768]^T
#define WS_WV1T  1106944    // [768][100]  W_v1^T
#define WS_BASE2 1183744    // [16][50][400] uint: packed bf16 pair, pre-scaled by 2log2e
#define WS_ODP2  1503744    // [32*16][100] (od@WODT)*2log2e
#define WS_ATTN  1554944    // [16][32][400]
#define WS_H1B   1759744    // [512][128] bf16 (stored as shorts) = 32768 float slots
#define WS_PGEN  1792512    // [512]
#define WS_VSUM  1793024    // [512]
#define WS_TOTAL 1793536

// ---- out offsets (floats) ----
#define OUT_CL   25625600
#define OUT_COV  25626112
#define OUT_HID  25632512
#define OUT_CELL 25640704
// first 8*512*512 floats of out are used as ctx-partial scratch (overwritten by vocab pass B later)
#define CTXP_SZ  262144

typedef __attribute__((ext_vector_type(8))) short bf16x8;
typedef __attribute__((ext_vector_type(4))) float f32x4;

__device__ __forceinline__ float fexp2(float x){ return __builtin_amdgcn_exp2f(x); }
__device__ __forceinline__ float frcp (float x){ return __builtin_amdgcn_rcpf(x); }
__device__ __forceinline__ float sigm (float x){ return frcp(1.f + fexp2(-L2E*x)); }
__device__ __forceinline__ float tanhx(float x){ return fmaf(-2.f, frcp(1.f + fexp2(L2E2*x)), 1.f); }
__device__ __forceinline__ unsigned short cvt_bf16(float x){
  unsigned u = __float_as_uint(x);
  u += 0x7FFFu + ((u >> 16) & 1u);
  return (unsigned short)(u >> 16);
}
__device__ __forceinline__ unsigned pack2bf(float lo, float hi){
  return ((unsigned)cvt_bf16(hi) << 16) | (unsigned)cvt_bf16(lo);
}

__device__ __forceinline__ float bredSum(float v, float* red){
  #pragma unroll
  for (int m = 32; m >= 1; m >>= 1) v += __shfl_xor(v, m);
  __syncthreads();
  if ((threadIdx.x & 63) == 0) red[threadIdx.x >> 6] = v;
  __syncthreads();
  float r = 0.f;
  int nw = blockDim.x >> 6;
  for (int k = 0; k < nw; ++k) r += red[k];
  return r;
}

// ---------------- prep: weight transposes + reduce_enc + small copies + enc_base ----------------
__global__ __launch_bounds__(256) void k_prep_enc(const float* __restrict__ he,
    const float* __restrict__ ce, const float* __restrict__ b_reduce,
    const float* __restrict__ W_reduce,
    const float* __restrict__ W_attn, const float* __restrict__ W_v1,
    const float* __restrict__ w_hh0, const float* __restrict__ w_ih1,
    const float* __restrict__ w_hh1,
    const float* __restrict__ enc, const float* __restrict__ b_attn,
    float* __restrict__ ws){
  int bx = blockIdx.x, tid = threadIdx.x;
  __shared__ float tile[64*65];
  __shared__ float encs[16][132];
  __shared__ float was[50][132];
  __shared__ float hA[256], hB[256], cA[256], cB[256];
  if (bx < 192){
    int m = bx >> 6, t6 = bx & 63;
    int kb = t6 & 3, cb = t6 >> 2;
    const float* src = (m == 0) ? w_hh0 : (m == 1) ? w_ih1 : w_hh1;
    int dstoff = (m == 0) ? WS_WT0 : (m == 1) ? WS_WTI1 : WS_WTH1;
    for (int o = tid; o < 4096; o += 256){
      int cc = o >> 6, kk = o & 63;
      int c = cb*64 + cc;
      int j = (c & 3)*256 + (c >> 2);
      tile[cc*65 + kk] = src[j*256 + kb*64 + kk];
    }
    __syncthreads();
    for (int o = tid; o < 4096; o += 256){
      int kk = o >> 6, cc = o & 63;
      ws[dstoff + (kb*64 + kk)*1024 + cb*64 + cc] = tile[cc*65 + kk];
    }
    return;
  }
  if (bx < 224){
    int bx2 = bx - 192;
    int l = bx2 >> 4, b = bx2 & 15, j = tid;
    hA[tid] = he[(l*B_ + b)*H_ + tid];
    hB[tid] = he[((l+2)*B_ + b)*H_ + tid];
    cA[tid] = ce[(l*B_ + b)*H_ + tid];
    cB[tid] = ce[((l+2)*B_ + b)*H_ + tid];
    __syncthreads();
    float ah = b_reduce[j], ac = b_reduce[j];
    const float4* row = (const float4*)(W_reduce + j*512);
    #pragma unroll 8
    for (int k4 = 0; k4 < 64; ++k4){
      float4 wa = row[k4];
      float4 wb = row[64 + k4];
      int k = k4*4;
      ah += wa.x*hA[k] + wa.y*hA[k+1] + wa.z*hA[k+2] + wa.w*hA[k+3];
      ac += wa.x*cA[k] + wa.y*cA[k+1] + wa.z*cA[k+2] + wa.w*cA[k+3];
      ah += wb.x*hB[k] + wb.y*hB[k+1] + wb.z*hB[k+2] + wb.w*hB[k+3];
      ac += wb.x*cB[k] + wb.y*cB[k+1] + wb.z*cB[k+2] + wb.w*cB[k+3];
    }
    if (l == 0){ ws[WS_H0S + j*16 + b] = ah; ws[WS_C0S + j*16 + b] = ac; }
    else       { ws[WS_H1S + j*16 + b] = ah; ws[WS_C1S + j*16 + b] = ac; }
    return;
  }
  if (bx < 626){
    int i = (bx - 224)*256 + tid;
    if (i < 25600){ int k = i/100, a = i%100; ws[WS_WODT + i] = W_attn[a*769 + 512 + k]; return; }
    i -= 25600;
    if (i < 76800){ int k = i/100, f = i%100; ws[WS_WV1T + i] = W_v1[f*768 + k]; return; }
    i -= 76800;
    if (i < 512){ ws[WS_VSUM + i] = 0.f; return; }
    return;
  }
  // ---- enc_base: packed bf16 [b][p2][s], value = (enc@Wattn + b_attn)*2log2e ----
  int r = bx - 626;                      // 800 = st + 25*(ah + 2*b)
  int st = r % 25, rem = r / 25;
  int ah = rem & 1, b = rem >> 1;
  int s_base = st*16;
  bool act = tid < 200;
  int sg = tid & 7, ag = tid >> 3;
  int sl = sg*2, al = ag*2;
  float acc00=0.f, acc01=0.f, acc10=0.f, acc11=0.f;
  for (int kc = 0; kc < 4; ++kc){
    int k0 = kc*128;
    __syncthreads();
    for (int o = tid; o < 512; o += 256){
      int rr = o >> 5, c4 = (o & 31)*4;
      float4 v = *(const float4*)(enc + ((s_base + rr)*B_ + b)*512 + k0 + c4);
      *(float4*)&encs[rr][c4] = v;
    }
    for (int o = tid; o < 6400; o += 256){
      int rr = o >> 7, c = o & 127;
      was[rr][c] = W_attn[(ah*50 + rr)*769 + k0 + c];
    }
    __syncthreads();
    if (act){
      for (int k = 0; k < 128; ++k){
        float e0 = encs[sl][k], e1 = encs[sl+1][k];
        float w0 = was[al][k],  w1 = was[al+1][k];
        acc00 = fmaf(e0, w0, acc00); acc01 = fmaf(e0, w1, acc01);
        acc10 = fmaf(e1, w0, acc10); acc11 = fmaf(e1, w1, acc11);
      }
    }
  }
  if (act){
    int a = ah*50 + al, s = s_base + sl;
    float b0 = b_attn[a], b1 = b_attn[a+1];
    int p2 = ah*25 + (al >> 1);
    unsigned* bu = (unsigned*)(ws + WS_BASE2) + b*20000;
    bu[p2*400 + s    ] = pack2bf((acc00 + b0)*L2E2, (acc01 + b1)*L2E2);
    bu[p2*400 + s + 1] = pack2bf((acc10 + b0)*L2E2, (acc11 + b1)*L2E2);
  }
}

// ---------------- LSTM phase p (split-K): WGs 0-63 layer0 step p (16 cols each, k-split 2),
// WGs 64-191 layer1 step p-1 (8 cols each, k-split 2) ----------------
__global__ __launch_bounds__(256, 1) void k_lstm4(const float* __restrict__ input_dec,
    const float* __restrict__ w_ih0, const float* __restrict__ b_ih0, const float* __restrict__ b_hh0,
    const float* __restrict__ b_ih1, const float* __restrict__ b_hh1,
    float* __restrict__ ws, float* __restrict__ out, int p){
  int wgs = blockIdx.x;
  int tid = threadIdx.x;
  __shared__ float hs[4096];
  __shared__ float ys[4096];
  __shared__ float gv[288];
  __shared__ float xs[16];
  if (wgs < 64){
    if (p >= T_) return;
    int w = wgs;
    int par = p & 1, npar = par ^ 1;
    for (int o = tid; o < 1024; o += 256)
      *(float4*)&hs[o*4] = *(const float4*)&ws[WS_H0S + par*4096 + o*4];
    if (tid < 16) xs[tid] = input_dec[p*16 + tid];
    __syncthreads();
    int ks = tid & 1, cl = (tid >> 1) & 15, bg = tid >> 5;  // 2 x 16 x 8
    int c = w*16 + cl;
    int g = cl & 3, h = w*4 + (cl >> 2);
    int j = g*256 + h;
    float a0, a1;
    if (ks == 0){
      float bias = b_ih0[j] + b_hh0[j];
      float wih = w_ih0[j];
      a0 = fmaf(xs[bg*2],   wih, bias);
      a1 = fmaf(xs[bg*2+1], wih, bias);
    } else { a0 = 0.f; a1 = 0.f; }
    const float* wp = ws + WS_WT0 + ks*131072 + c;
    const float* hp = hs + ks*2048 + bg*2;
    #pragma unroll 16
    for (int k = 0; k < 128; ++k){
      float wv = wp[k*1024];
      float2 hv = *(const float2*)&hp[k*16];
      a0 = fmaf(wv, hv.x, a0); a1 = fmaf(wv, hv.y, a1);
    }
    a0 += __shfl_xor(a0, 1);
    a1 += __shfl_xor(a1, 1);
    if (ks == 0){
      gv[cl*18 + bg*2    ] = a0;
      gv[cl*18 + bg*2 + 1] = a1;
    }
    __syncthreads();
    if (tid < 64){
      int b = tid & 15, hl = tid >> 4;       // hl 0..3
      float gi = gv[(hl*4+0)*18 + b], gf = gv[(hl*4+1)*18 + b];
      float gg = gv[(hl*4+2)*18 + b], go = gv[(hl*4+3)*18 + b];
      int hidx = w*4 + hl;
      float cold = ws[WS_C0S + par*4096 + hidx*16 + b];
      float ig = sigm(gi), fg = sigm(gf), gt = tanhx(gg), og = sigm(go);
      float cn = fmaf(fg, cold, ig*gt);
      float hn = og * tanhx(cn);
      ws[WS_C0S + npar*4096 + hidx*16 + b] = cn;
      ws[WS_H0S + npar*4096 + hidx*16 + b] = hn;
      ws[WS_Y0 + p*4096 + hidx*16 + b] = hn;
      if (p == T_-1){
        out[OUT_HID  + b*256 + hidx] = hn;
        out[OUT_CELL + b*256 + hidx] = cn;
      }
    }
  } else {
    int q = p - 1;
    if (q < 0) return;
    int u = wgs - 64;                        // 0..127
    int par = q & 1, npar = par ^ 1;
    for (int o = tid; o < 1024; o += 256){
      *(float4*)&ys[o*4] = *(const float4*)&ws[WS_Y0 + q*4096 + o*4];
      *(float4*)&hs[o*4] = *(const float4*)&ws[WS_H1S + par*4096 + o*4];
    }
    __syncthreads();
    int ks = tid & 1, cl = (tid >> 1) & 7, b = tid >> 4;   // 2 x 8 x 16
    int c = u*8 + cl;
    int g = cl & 3, h = u*2 + (cl >> 2);
    int j = g*256 + h;
    float ai = (ks == 0) ? (b_ih1[j] + b_hh1[j]) : 0.f;
    float ah2 = 0.f;
    const float* wi = ws + WS_WTI1 + ks*131072 + c;
    const float* wh = ws + WS_WTH1 + ks*131072 + c;
    const float* yp = ys + ks*2048 + b;
    const float* hp = hs + ks*2048 + b;
    #pragma unroll 16
    for (int k = 0; k < 128; ++k){
      ai  = fmaf(wi[k*1024], yp[k*16], ai);
      ah2 = fmaf(wh[k*1024], hp[k*16], ah2);
    }
    float tot = ai + ah2;
    tot += __shfl_xor(tot, 1);
    if (ks == 0) gv[cl*17 + b] = tot;
    __syncthreads();
    if (tid < 32){
      int b2 = tid & 15, hl = tid >> 4;      // hl 0..1
      float gi = gv[(hl*4+0)*17 + b2], gf = gv[(hl*4+1)*17 + b2];
      float gg = gv[(hl*4+2)*17 + b2], go = gv[(hl*4+3)*17 + b2];
      int hidx = u*2 + hl;
      float cold = ws[WS_C1S + par*4096 + hidx*16 + b2];
      float ig = sigm(gi), fg = sigm(gf), gt = tanhx(gg), og = sigm(go);
      float cn = fmaf(fg, cold, ig*gt);
      float hn = og * tanhx(cn);
      ws[WS_C1S + npar*4096 + hidx*16 + b2] = cn;
      ws[WS_H1S + npar*4096 + hidx*16 + b2] = hn;
      ws[WS_OD + q*4096 + hidx*16 + b2] = hn;
      if (q == T_-1){
        out[OUT_HID  + 4096 + b2*256 + hidx] = hn;
        out[OUT_CELL + 4096 + b2*256 + hidx] = cn;
      }
    }
  }
}

// ---------------- odp2[t*16+b][a] = (od @ W_attn[:,512:768]^T) * 2log2e ----------------
__global__ __launch_bounds__(256) void k_odp(float* __restrict__ ws){
  int row = blockIdx.x;        // 512 = t*16+b
  int t = row >> 4, b = row & 15;
  int tid = threadIdx.x;
  __shared__ float odl[256];
  odl[tid] = ws[WS_OD + t*4096 + tid*16 + b];
  __syncthreads();
  if (tid < 100){
    float acc = 0.f;
    for (int k = 0; k < 256; ++k) acc = fmaf(ws[WS_WODT + k*100 + tid], odl[k], acc);
    ws[WS_ODP2 + row*100 + tid] = acc * L2E2;
  }
}

// ---------------- attention recurrence v8: one WG per batch, ONE barrier/step,
// half-pair in same wave (shfl_xor 32), base2 LDS bf16,
// register-prefetched odp row, per-wave den/cls slots (no LDS atomics) ----------------
__global__ __launch_bounds__(832) void k_attn(const float* __restrict__ amask,
    const float* __restrict__ W_attn, const float* __restrict__ wout_g,
    float* __restrict__ out, float* __restrict__ ws){
  int b = blockIdx.x;
  int tid = threadIdx.x;
  int w = tid >> 6, l = tid & 63;
  int sl = l & 31, half = l >> 5;
  int s = w*32 + sl;                      // 13 waves cover s<416
  bool valid = s < 400;
  int h25 = half*25, a0 = half*50;
  __shared__ unsigned ba2L[20000];        // [p2 0..49][s 0..399] packed bf16 pair
  __shared__ float4 f4[2][100];
  __shared__ float wcwo[200];
  __shared__ float denp[2][13], clsp[2][13];
  const unsigned* src = (const unsigned*)(ws + WS_BASE2) + b*20000;
  for (int o = tid; o < 20000; o += 832) ba2L[o] = src[o];
  if (tid < 100){
    wcwo[tid]       = W_attn[tid*769 + 768] * L2E2;
    wcwo[100 + tid] = -2.f * wout_g[tid];
  }
  if (tid < 26){ denp[tid & 1][tid >> 1] = 0.f; clsp[tid & 1][tid >> 1] = 0.f; }
  float woSum = 0.f;
  #pragma unroll 10
  for (int a = 0; a < 100; ++a) woSum += wout_g[a];
  float amL = valid ? amask[s*16 + b] * L2E : 0.f;
  float cov = 0.f;
  int sI = valid ? s : 0;
  __syncthreads();
  if (tid < 100){
    float od = ws[WS_ODP2 + b*100 + tid];   // t=0 row
    f4[0][tid] = make_float4(od, wcwo[tid], wcwo[100 + tid], 0.f);
  }
  __syncthreads();

  for (int t = 0; t < T_; ++t){
    int par = t & 1;
    // issue next-step odp load EARLY (hides under ep compute)
    float odreg = 0.f;
    if (tid < 100 && t < T_-1)
      odreg = ws[WS_ODP2 + ((t+1)*16 + b)*100 + tid];
    float ep0 = 0.f, ep1 = 0.f;
    if (valid){
      #pragma unroll
      for (int i2 = 0; i2 < 25; ++i2){
        unsigned d = ba2L[(h25 + i2)*400 + sI];
        float4 qa = f4[par][a0 + 2*i2];
        float4 qb = f4[par][a0 + 2*i2 + 1];
        float blo = __uint_as_float(d << 16);
        float bhi = __uint_as_float(d & 0xffff0000u);
        float xa = fmaf(qa.y, cov, blo + qa.x);
        float xb = fmaf(qb.y, cov, bhi + qb.x);
        ep0 = fmaf(qa.z, frcp(1.f + fexp2(xa)), ep0);
        ep1 = fmaf(qb.z, frcp(1.f + fexp2(xb)), ep1);
      }
    }
    float e = ep0 + ep1;
    e += __shfl_xor(e, 32);               // combine the two a-halves of this s
    float ex = 0.f;
    if (valid) ex = fexp2(fmaf(woSum + e, L2E, amL));
    float ps = half ? 0.f : ex;
    #pragma unroll
    for (int m = 32; m >= 1; m >>= 1) ps += __shfl_xor(ps, m);
    if (l == 0) denp[par][w] = ps;
    if (tid < 100 && t < T_-1)
      f4[par^1][tid] = make_float4(odreg, wcwo[tid], wcwo[100 + tid], 0.f);
    __syncthreads();                      // denp[par] ready; f4[par^1] ready
    float den = 0.f;
    #pragma unroll
    for (int w2 = 0; w2 < 13; ++w2) den += denp[par][w2];
    float inv = frcp(den);
    float at = ex * inv;
    float cl = fminf(at, cov);
    cov += at;
    float p2 = half ? 0.f : cl;
    #pragma unroll
    for (int m = 32; m >= 1; m >>= 1) p2 += __shfl_xor(p2, m);
    if (l == 0) clsp[par][w] = p2;
    if (half == 0 && valid) ws[WS_ATTN + (b*32 + t)*400 + s] = at;
    if (tid == 0 && t > 0){
      float cls = 0.f;
      #pragma unroll
      for (int w2 = 0; w2 < 13; ++w2) cls += clsp[par^1][w2];
      out[OUT_CL + (t-1)*16 + b] = cls;
    }
  }
  __syncthreads();
  if (tid == 0){
    float cls = 0.f;
    #pragma unroll
    for (int w2 = 0; w2 < 13; ++w2) cls += clsp[1][w2];
    out[OUT_CL + 31*16 + b] = cls;
  }
  if (half == 0 && valid) out[OUT_COV + s*16 + b] = cov;
}

// ---------------- context partials into out-scratch: ctxp[sc][t*16+b][512] ----------------
__global__ __launch_bounds__(256) void k_ctx(const float* __restrict__ enc,
    const float* __restrict__ ws, float* __restrict__ ctxp){
  int b = blockIdx.x, jh = blockIdx.y, sc = blockIdx.z;   // (16,2,8)
  int tid = threadIdx.x;
  __shared__ float at[32*52];
  for (int o = tid; o < 1600; o += 256){
    int t = o/50, s2 = o%50;
    at[t*52 + s2] = ws[WS_ATTN + (b*32 + t)*400 + sc*50 + s2];
  }
  __syncthreads();
  int j = jh*256 + tid;
  float acc[32];
  #pragma unroll
  for (int t = 0; t < 32; ++t) acc[t] = 0.f;
  for (int s2 = 0; s2 < 50; ++s2){
    float evv = enc[((sc*50 + s2)*16 + b)*512 + j];
    #pragma unroll
    for (int t = 0; t < 32; ++t) acc[t] = fmaf(at[t*52 + s2], evv, acc[t]);
  }
  #pragma unroll
  for (int t = 0; t < 32; ++t)
    ctxp[sc*CTXP_SZ + (t*16 + b)*512 + j] = acc[t];
}

// ---------------- pgen + h1 (vocab hidden, bf16 padded) per (t,b) ----------------
__global__ __launch_bounds__(256) void k_pgen_h1(const float* __restrict__ input_dec,
    const float* __restrict__ emb, const float* __restrict__ b_v1,
    const float* __restrict__ W_pgen, const float* __restrict__ b_pgen,
    const float* __restrict__ ctxp, float* __restrict__ ws){
  int row = blockIdx.x, tid = threadIdx.x;
  int t = row >> 4, b = row & 15;
  __shared__ float pv[768], el[50], red[16];
  pv[tid] = ws[WS_OD + t*4096 + tid*16 + b];
  float c0 = 0.f, c1 = 0.f;
  #pragma unroll
  for (int sc = 0; sc < 8; ++sc){
    c0 += ctxp[sc*CTXP_SZ + row*512 + tid];
    c1 += ctxp[sc*CTXP_SZ + row*512 + 256 + tid];
  }
  pv[256 + tid] = c0;
  pv[512 + tid] = c1;
  int tok = (int)input_dec[row];
  if (tid < 50) el[tid] = emb[tok*50 + tid];
  __syncthreads();
  float p = 0.f;
  for (int k = tid; k < 818; k += 256){
    float x = (k < 512) ? pv[256 + k] : (k < 768) ? pv[k - 512] : el[k - 768];
    p = fmaf(W_pgen[k], x, p);
  }
  p = bredSum(p, red);
  if (tid == 0) ws[WS_PGEN + row] = sigm(p + b_pgen[0]);
  short* hb = (short*)(ws + WS_H1B);
  if (tid < 100){
    float acc = b_v1[tid];
    for (int k = 0; k < 768; ++k) acc = fmaf(ws[WS_WV1T + k*100 + tid], pv[k], acc);
    hb[row*128 + tid] = (short)cvt_bf16(acc);
  } else if (tid < 128){
    hb[row*128 + tid] = 0;
  }
}

// ---------------- pass A: per-row exp2-sums, LDS-staged bf16 W_v2 tile ----------------
__global__ __launch_bounds__(256) void k_vsum(const float* __restrict__ W_v2,
    const float* __restrict__ b_v2, float* __restrict__ ws){
  int tid = threadIdx.x;
  int wave = tid >> 6, l = tid & 63;
  int lane_m = l & 15, lq = l >> 4;
  int vblock0 = blockIdx.x*256;
  int r0base = blockIdx.y*256;
  __shared__ short wt[256*136];          // rows padded to 136 shorts (272B)
  __shared__ float biasL[256];
  __shared__ float rsum[256];
  for (int o = tid; o < 4352; o += 256)
    ((int4*)wt)[o] = make_int4(0,0,0,0);
  {
    int v = vblock0 + tid;
    biasL[tid] = (v < V_) ? b_v2[v] : 0.f;
    rsum[tid] = 0.f;
  }
  __syncthreads();
  int vcount = V_ - vblock0; if (vcount > 256) vcount = 256;
  for (int o = tid; o < vcount*25; o += 256){
    int r = o/25, kq = o - r*25;
    float4 v4 = *(const float4*)(W_v2 + (size_t)(vblock0 + r)*100 + kq*4);
    short4 s4;
    s4.x = (short)cvt_bf16(v4.x); s4.y = (short)cvt_bf16(v4.y);
    s4.z = (short)cvt_bf16(v4.z); s4.w = (short)cvt_bf16(v4.w);
    *(short4*)&wt[r*136 + kq*4] = s4;
  }
  __syncthreads();
  bf16x8 bf[4][4];
  float bias[4];
  int vv[4];
  #pragma unroll
  for (int nt = 0; nt < 4; ++nt){
    int vl = wave*64 + nt*16 + lane_m;
    vv[nt] = vblock0 + vl;
    bias[nt] = biasL[vl];
    #pragma unroll
    for (int kk = 0; kk < 4; ++kk)
      bf[nt][kk] = *(const bf16x8*)&wt[vl*136 + kk*32 + lq*8];
  }
  const short* hws = (const short*)(ws + WS_H1B);
  for (int rg = 0; rg < 16; ++rg){
    int r0 = r0base + rg*16;
    bf16x8 af[4];
    #pragma unroll
    for (int kk = 0; kk < 4; ++kk)
      af[kk] = *(const bf16x8*)(hws + (r0 + lane_m)*128 + kk*32 + lq*8);
    float es[4] = {0.f, 0.f, 0.f, 0.f};
    #pragma unroll
    for (int nt = 0; nt < 4; ++nt){
      f32x4 c = {bias[nt], bias[nt], bias[nt], bias[nt]};
      #pragma unroll
      for (int kk = 0; kk < 4; ++kk)
        c = __builtin_amdgcn_mfma_f32_16x16x32_bf16(af[kk], bf[nt][kk], c, 0, 0, 0);
      if (vv[nt] < V_){
        #pragma unroll
        for (int j = 0; j < 4; ++j) es[j] += fexp2(c[j] * L2E);
      }
    }
    #pragma unroll
    for (int m = 1; m <= 8; m <<= 1){
      #pragma unroll
      for (int j = 0; j < 4; ++j) es[j] += __shfl_xor(es[j], m);
    }
    if (lane_m == 0){
      #pragma unroll
      for (int j = 0; j < 4; ++j)
        atomicAdd(&rsum[rg*16 + lq*4 + j], es[j]);
    }
  }
  __syncthreads();
  atomicAdd(ws + WS_VSUM + r0base + tid, rsum[tid]);
}

// ---------------- pass B: recompute logits, write softmax*pgen, LDS-staged tile + coalesced stores ----------------
__global__ __launch_bounds__(256) void k_vwrite(const float* __restrict__ W_v2,
    const float* __restrict__ b_v2, const float* __restrict__ ws, float* __restrict__ out){
  int tid = threadIdx.x;
  int wave = tid >> 6, l = tid & 63;
  int lane_m = l & 15, lq = l >> 4;
  int vblock0 = blockIdx.x*256;
  int r0base = blockIdx.y*256;
  __shared__ short wt[256*136];
  __shared__ float biasL[256];
  __shared__ float scs[256];
  __shared__ float stg[16][260];
  for (int o = tid; o < 4352; o += 256)
    ((int4*)wt)[o] = make_int4(0,0,0,0);
  {
    int v = vblock0 + tid;
    biasL[tid] = (v < V_) ? b_v2[v] : 0.f;
    int r = r0base + tid;
    scs[tid] = ws[WS_PGEN + r] / ws[WS_VSUM + r];
  }
  __syncthreads();
  int vcount = V_ - vblock0; if (vcount > 256) vcount = 256;
  for (int o = tid; o < vcount*25; o += 256){
    int r = o/25, kq = o - r*25;
    float4 v4 = *(const float4*)(W_v2 + (size_t)(vblock0 + r)*100 + kq*4);
    short4 s4;
    s4.x = (short)cvt_bf16(v4.x); s4.y = (short)cvt_bf16(v4.y);
    s4.z = (short)cvt_bf16(v4.z); s4.w = (short)cvt_bf16(v4.w);
    *(short4*)&wt[r*136 + kq*4] = s4;
  }
  __syncthreads();
  bf16x8 bf[4][4];
  float bias[4];
  int vv[4];
  #pragma unroll
  for (int nt = 0; nt < 4; ++nt){
    int vl = wave*64 + nt*16 + lane_m;
    vv[nt] = vblock0 + vl;
    bias[nt] = biasL[vl];
    #pragma unroll
    for (int kk = 0; kk < 4; ++kk)
      bf[nt][kk] = *(const bf16x8*)&wt[vl*136 + kk*32 + lq*8];
  }
  const short* hws = (const short*)(ws + WS_H1B);
  int limit = BV_ - vblock0;            // valid col count in [0,256]
  if (limit > 256) limit = 256;
  for (int rg = 0; rg < 16; ++rg){
    int r0 = r0base + rg*16;
    bf16x8 af[4];
    #pragma unroll
    for (int kk = 0; kk < 4; ++kk)
      af[kk] = *(const bf16x8*)(hws + (r0 + lane_m)*128 + kk*32 + lq*8);
    #pragma unroll
    for (int nt = 0; nt < 4; ++nt){
      f32x4 c = {bias[nt], bias[nt], bias[nt], bias[nt]};
      #pragma unroll
      for (int kk = 0; kk < 4; ++kk)
        c = __builtin_amdgcn_mfma_f32_16x16x32_bf16(af[kk], bf[nt][kk], c, 0, 0, 0);
      bool gen = vv[nt] < V_;
      #pragma unroll
      for (int j = 0; j < 4; ++j){
        int rloc = lq*4 + j;
        float p = gen ? fexp2(c[j] * L2E) * scs[rg*16 + rloc] : 0.f;
        stg[rloc][wave*64 + nt*16 + lane_m] = p;
      }
    }
    __syncthreads();
    #pragma unroll
    for (int rep = 0; rep < 4; ++rep){
      int o = rep*256 + tid;
      int rr = o >> 6, c4 = (o & 63)*4;
      size_t base = (size_t)(r0base + rg*16 + rr)*BV_ + vblock0;
      if (c4 + 4 <= limit){
        float4 val = *(const float4*)&stg[rr][c4];
        *(float4*)&out[base + c4] = val;
      } else {
        for (int e = 0; e < 4; ++e)
          if (c4 + e < limit) out[base + c4 + e] = stg[rr][c4 + e];
      }
    }
    __syncthreads();
  }
}

// ---------------- copy-distribution scatter ----------------
__global__ __launch_bounds__(256) void k_scatter(const int* __restrict__ real_index,
    const float* __restrict__ ws, float* __restrict__ out){
  int i = blockIdx.x*256 + threadIdx.x;   // 16*32*400
  int b = i / 12800, r = i % 12800, t = r / 400, s = r % 400;
  float at = ws[WS_ATTN + i];
  float w = 1.f - ws[WS_PGEN + t*16 + b];
  int col = real_index[s*16 + b];
  atomicAdd(out + (size_t)(t*16 + b)*BV_ + col, at*w);
}

extern "C" void kernel_launch(void* const* d_in, const int* in_sizes, int n_in,
                              void* d_out, int out_size, void* d_ws, size_t ws_size,
                              hipStream_t stream){
  const float* output_enc = (const float*)d_in[0];
  const int*   real_index = (const int*)d_in[1];
  const float* input_dec  = (const float*)d_in[3];
  const float* hidden_enc = (const float*)d_in[4];
  const float* cell_enc   = (const float*)d_in[5];
  const float* att_mask   = (const float*)d_in[6];
  const float* emb        = (const float*)d_in[7];
  const float* W_reduce   = (const float*)d_in[8];
  const float* b_reduce   = (const float*)d_in[9];
  const float* w_ih0      = (const float*)d_in[10];
  const float* w_hh0      = (const float*)d_in[11];
  const float* b_ih0      = (const float*)d_in[12];
  const float* b_hh0      = (const float*)d_in[13];
  const float* w_ih1      = (const float*)d_in[14];
  const float* w_hh1      = (const float*)d_in[15];
  const float* b_ih1      = (const float*)d_in[16];
  const float* b_hh1      = (const float*)d_in[17];
  const float* W_attn     = (const float*)d_in[18];
  const float* b_attn     = (const float*)d_in[19];
  const float* w_attn_out = (const float*)d_in[20];
  const float* W_v1       = (const float*)d_in[21];
  const float* b_v1       = (const float*)d_in[22];
  const float* W_v2       = (const float*)d_in[23];
  const float* b_v2       = (const float*)d_in[24];
  const float* W_pgen     = (const float*)d_in[25];
  const float* b_pgen     = (const float*)d_in[26];
  float* out = (float*)d_out;
  float* ws  = (float*)d_ws;
  if (ws_size < (size_t)WS_TOTAL * sizeof(float)) return;

  k_prep_enc<<<dim3(1426), dim3(256), 0, stream>>>(hidden_enc, cell_enc, b_reduce, W_reduce,
                                                   W_attn, W_v1, w_hh0, w_ih1, w_hh1,
                                                   output_enc, b_attn, ws);
  for (int p = 0; p <= T_; ++p)
    k_lstm4<<<dim3(192), dim3(256), 0, stream>>>(input_dec, w_ih0, b_ih0, b_hh0,
                                                 b_ih1, b_hh1, ws, out, p);
  k_odp<<<dim3(512), dim3(256), 0, stream>>>(ws);
  k_attn<<<dim3(16), dim3(832), 0, stream>>>(att_mask, W_attn, w_attn_out, out, ws);
  k_ctx<<<dim3(16, 2, 8), dim3(256), 0, stream>>>(output_enc, ws, out);
  k_pgen_h1<<<dim3(512), dim3(256), 0, stream>>>(input_dec, emb, b_v1, W_pgen, b_pgen, out, ws);
  k_vsum<<<dim3(196, 2), dim3(256), 0, stream>>>(W_v2, b_v2, ws);
  k_vwrite<<<dim3(196, 2), dim3(256), 0, stream>>>(W_v2, b_v2, ws, out);
  k_scatter<<<dim3(800), dim3(256), 0, stream>>>(real_index, ws, out);
}